// Round 2
// baseline (1823.176 us; speedup 1.0000x reference)
//
#include <hip/hip_runtime.h>
#include <hip/hip_bf16.h>

// Problem constants (setup_inputs is fixed)
#define S_LEN 2048
#define BATCH 2
#define EMB   1024
#define NHEAD 16
#define HDIM  64
#define WIN   128

// ---------------------------------------------------------------------------
// QKV projection: Y[r,n] = sum_k X[r,k] * W[n,k] + bias[n]   (f32 in, f32 out)
// X: [S*B, E] (one of query/key/value picked by blockIdx.z)
// W slice: [E, E] row-major, bias slice: [E]
// Output layout: [B, H, S, D] f32 ; q additionally scaled by 1/sqrt(D)
// Tiles: BM=BN=64, BK=16; 256 threads; 4x4 micro-tile per thread.
// ---------------------------------------------------------------------------
__global__ __launch_bounds__(256)
void qkv_gemm_kernel(const float* __restrict__ xq,
                     const float* __restrict__ xk,
                     const float* __restrict__ xv,
                     const float* __restrict__ w,     // [3E, E]
                     const float* __restrict__ bias,  // [3E]
                     float* __restrict__ qw,
                     float* __restrict__ kw,
                     float* __restrict__ vw)
{
    __shared__ float As[64][17];
    __shared__ float Bs[64][17];

    const int which = blockIdx.z;
    const float* A  = (which == 0) ? xq : (which == 1) ? xk : xv;
    const float* W  = w + (size_t)which * EMB * EMB;
    const float* bv = bias + which * EMB;
    float* out = (which == 0) ? qw : (which == 1) ? kw : vw;
    const float scale = (which == 0) ? 0.125f : 1.0f;  // 1/sqrt(64)

    const int tid = threadIdx.x;
    const int tx = tid & 15;
    const int ty = tid >> 4;
    const int rowBase = blockIdx.y * 64;
    const int colBase = blockIdx.x * 64;

    const int lrow = tid >> 2;          // 0..63
    const int lcol = (tid & 3) << 2;    // 0,4,8,12

    float acc[4][4] = {{0.f,0.f,0.f,0.f},{0.f,0.f,0.f,0.f},
                       {0.f,0.f,0.f,0.f},{0.f,0.f,0.f,0.f}};

    const float* aptr = A + (size_t)(rowBase + lrow) * EMB + lcol;
    const float* bptr = W + (size_t)(colBase + lrow) * EMB + lcol;

    for (int k0 = 0; k0 < EMB; k0 += 16) {
        float4 ar = *reinterpret_cast<const float4*>(aptr + k0);
        float4 br = *reinterpret_cast<const float4*>(bptr + k0);
        As[lrow][lcol + 0] = ar.x;
        As[lrow][lcol + 1] = ar.y;
        As[lrow][lcol + 2] = ar.z;
        As[lrow][lcol + 3] = ar.w;
        Bs[lrow][lcol + 0] = br.x;
        Bs[lrow][lcol + 1] = br.y;
        Bs[lrow][lcol + 2] = br.z;
        Bs[lrow][lcol + 3] = br.w;
        __syncthreads();

        #pragma unroll
        for (int kk = 0; kk < 16; ++kk) {
            float a0 = As[ty * 4 + 0][kk];
            float a1 = As[ty * 4 + 1][kk];
            float a2 = As[ty * 4 + 2][kk];
            float a3 = As[ty * 4 + 3][kk];
            float b0 = Bs[tx * 4 + 0][kk];
            float b1 = Bs[tx * 4 + 1][kk];
            float b2 = Bs[tx * 4 + 2][kk];
            float b3 = Bs[tx * 4 + 3][kk];
            acc[0][0] += a0 * b0; acc[0][1] += a0 * b1; acc[0][2] += a0 * b2; acc[0][3] += a0 * b3;
            acc[1][0] += a1 * b0; acc[1][1] += a1 * b1; acc[1][2] += a1 * b2; acc[1][3] += a1 * b3;
            acc[2][0] += a2 * b0; acc[2][1] += a2 * b1; acc[2][2] += a2 * b2; acc[2][3] += a2 * b3;
            acc[3][0] += a3 * b0; acc[3][1] += a3 * b1; acc[3][2] += a3 * b2; acc[3][3] += a3 * b3;
        }
        __syncthreads();
    }

    #pragma unroll
    for (int i = 0; i < 4; ++i) {
        const int r = rowBase + ty * 4 + i;
        const int srow = r >> 1;     // r = s*B + b, B=2
        const int bb = r & 1;
        #pragma unroll
        for (int j = 0; j < 4; ++j) {
            const int n = colBase + tx * 4 + j;
            const float c = (acc[i][j] + bv[n]) * scale;
            const int h = n >> 6;    // n = h*64 + d
            const int d = n & 63;
            out[(((size_t)(bb * NHEAD + h) * S_LEN + srow) << 6) + d] = c;
        }
    }
}

// ---------------------------------------------------------------------------
// Banded attention, one wave (64 lanes) per (b*H+h, s). lane == d.
// q/k/v: [B,H,S,D] f32 (q pre-scaled). ctx out: [S,B,E] f32.
// ---------------------------------------------------------------------------
__global__ __launch_bounds__(64)
void attn_kernel(const float* __restrict__ q,
                 const float* __restrict__ k,
                 const float* __restrict__ v,
                 float* __restrict__ ctx)
{
    const int s    = blockIdx.x;
    const int bh   = blockIdx.y;          // b*NHEAD + h
    const int lane = threadIdx.x;

    const size_t rowbase = ((size_t)bh * S_LEN) << 6;   // * HDIM
    const float qd = q[rowbase + ((size_t)s << 6) + lane];

    int jlo = s - WIN;     if (jlo < 0) jlo = 0;
    int jhi = s + WIN - 1; if (jhi > S_LEN - 1) jhi = S_LEN - 1;

    float m = -1e30f, l = 0.f, acc = 0.f;
    for (int j = jlo; j <= jhi; ++j) {
        float sc = qd * k[rowbase + ((size_t)j << 6) + lane];
        #pragma unroll
        for (int off = 32; off >= 1; off >>= 1)
            sc += __shfl_xor(sc, off, 64);
        const float mn = fmaxf(m, sc);
        const float p  = __expf(sc - mn);
        const float al = __expf(m - mn);
        const float vv = v[rowbase + ((size_t)j << 6) + lane];
        l   = l * al + p;
        acc = acc * al + p * vv;
        m = mn;
    }

    const int b = bh >> 4;     // / NHEAD
    const int h = bh & 15;     // % NHEAD
    ctx[((size_t)(s * BATCH + b) << 10) + (h << 6) + lane] = acc / l;
}

// ---------------------------------------------------------------------------
// Output projection: out[r,n] = sum_k ctx[r,k] * W[n,k] + bias[n] -> f32
// ctx: [S*B, E] f32 ; W: [E,E] f32 ; out: [S,B,E] f32
// ---------------------------------------------------------------------------
__global__ __launch_bounds__(256)
void out_gemm_kernel(const float* __restrict__ ctx,
                     const float* __restrict__ w,
                     const float* __restrict__ bias,
                     float* __restrict__ out)
{
    __shared__ float As[64][17];
    __shared__ float Bs[64][17];

    const int tid = threadIdx.x;
    const int tx = tid & 15;
    const int ty = tid >> 4;
    const int rowBase = blockIdx.y * 64;
    const int colBase = blockIdx.x * 64;

    const int lrow = tid >> 2;
    const int lcol = (tid & 3) << 2;

    float acc[4][4] = {{0.f,0.f,0.f,0.f},{0.f,0.f,0.f,0.f},
                       {0.f,0.f,0.f,0.f},{0.f,0.f,0.f,0.f}};

    const float* aptr = ctx + (size_t)(rowBase + lrow) * EMB + lcol;
    const float* bptr = w + (size_t)(colBase + lrow) * EMB + lcol;

    for (int k0 = 0; k0 < EMB; k0 += 16) {
        float4 ar = *reinterpret_cast<const float4*>(aptr + k0);
        float4 br = *reinterpret_cast<const float4*>(bptr + k0);
        As[lrow][lcol + 0] = ar.x;
        As[lrow][lcol + 1] = ar.y;
        As[lrow][lcol + 2] = ar.z;
        As[lrow][lcol + 3] = ar.w;
        Bs[lrow][lcol + 0] = br.x;
        Bs[lrow][lcol + 1] = br.y;
        Bs[lrow][lcol + 2] = br.z;
        Bs[lrow][lcol + 3] = br.w;
        __syncthreads();

        #pragma unroll
        for (int kk = 0; kk < 16; ++kk) {
            float a0 = As[ty * 4 + 0][kk];
            float a1 = As[ty * 4 + 1][kk];
            float a2 = As[ty * 4 + 2][kk];
            float a3 = As[ty * 4 + 3][kk];
            float b0 = Bs[tx * 4 + 0][kk];
            float b1 = Bs[tx * 4 + 1][kk];
            float b2 = Bs[tx * 4 + 2][kk];
            float b3 = Bs[tx * 4 + 3][kk];
            acc[0][0] += a0 * b0; acc[0][1] += a0 * b1; acc[0][2] += a0 * b2; acc[0][3] += a0 * b3;
            acc[1][0] += a1 * b0; acc[1][1] += a1 * b1; acc[1][2] += a1 * b2; acc[1][3] += a1 * b3;
            acc[2][0] += a2 * b0; acc[2][1] += a2 * b1; acc[2][2] += a2 * b2; acc[2][3] += a2 * b3;
            acc[3][0] += a3 * b0; acc[3][1] += a3 * b1; acc[3][2] += a3 * b2; acc[3][3] += a3 * b3;
        }
        __syncthreads();
    }

    #pragma unroll
    for (int i = 0; i < 4; ++i) {
        const int r = rowBase + ty * 4 + i;
        #pragma unroll
        for (int j = 0; j < 4; ++j) {
            const int n = colBase + tx * 4 + j;
            out[(size_t)r * EMB + n] = acc[i][j] + bias[n];
        }
    }
}

// ---------------------------------------------------------------------------
extern "C" void kernel_launch(void* const* d_in, const int* in_sizes, int n_in,
                              void* d_out, int out_size, void* d_ws, size_t ws_size,
                              hipStream_t stream) {
    const float* query = (const float*)d_in[0];
    const float* key   = (const float*)d_in[1];
    const float* value = (const float*)d_in[2];
    const float* in_w  = (const float*)d_in[3];
    const float* in_b  = (const float*)d_in[4];
    const float* out_w = (const float*)d_in[5];
    const float* out_b = (const float*)d_in[6];
    // d_in[7] = num_heads (16), d_in[8] = block_size (128): baked as constants.

    // Workspace: q,k,v [B,H,S,D] f32 + ctx [S*B,E] f32 = 4 * 16 MB = 64 MB
    const size_t PLANE = (size_t)BATCH * NHEAD * S_LEN * HDIM;  // 4194304
    float* qw = (float*)d_ws;
    float* kw = qw + PLANE;
    float* vw = kw + PLANE;
    float* cw = vw + PLANE;

    dim3 g1(EMB / 64, (S_LEN * BATCH) / 64, 3);
    qkv_gemm_kernel<<<g1, 256, 0, stream>>>(query, key, value, in_w, in_b, qw, kw, vw);

    dim3 g2(S_LEN, BATCH * NHEAD);
    attn_kernel<<<g2, 64, 0, stream>>>(qw, kw, vw, cw);

    dim3 g3(EMB / 64, (S_LEN * BATCH) / 64);
    out_gemm_kernel<<<g3, 256, 0, stream>>>(cw, out_w, out_b, (float*)d_out);
}

// Round 3
// 902.455 us; speedup vs baseline: 2.0202x; 2.0202x over previous
//
#include <hip/hip_runtime.h>
#include <hip/hip_bf16.h>

// Problem constants (setup_inputs is fixed)
#define S_LEN 2048
#define BATCH 2
#define EMB   1024
#define NHEAD 16
#define HDIM  64
#define WIN   128

// ---------------------------------------------------------------------------
// QKV projection: Y[r,n] = sum_k X[r,k] * W[n,k] + bias[n]   (f32 in, f32 out)
// Output layout: [B, H, S, D] f32 ; q additionally scaled by 1/sqrt(D)
// Tiles: BM=BN=64, BK=16; 256 threads; 4x4 micro-tile per thread.
// ---------------------------------------------------------------------------
__global__ __launch_bounds__(256)
void qkv_gemm_kernel(const float* __restrict__ xq,
                     const float* __restrict__ xk,
                     const float* __restrict__ xv,
                     const float* __restrict__ w,     // [3E, E]
                     const float* __restrict__ bias,  // [3E]
                     float* __restrict__ qw,
                     float* __restrict__ kw,
                     float* __restrict__ vw)
{
    __shared__ float As[64][17];
    __shared__ float Bs[64][17];

    const int which = blockIdx.z;
    const float* A  = (which == 0) ? xq : (which == 1) ? xk : xv;
    const float* W  = w + (size_t)which * EMB * EMB;
    const float* bv = bias + which * EMB;
    float* out = (which == 0) ? qw : (which == 1) ? kw : vw;
    const float scale = (which == 0) ? 0.125f : 1.0f;  // 1/sqrt(64)

    const int tid = threadIdx.x;
    const int tx = tid & 15;
    const int ty = tid >> 4;
    const int rowBase = blockIdx.y * 64;
    const int colBase = blockIdx.x * 64;

    const int lrow = tid >> 2;          // 0..63
    const int lcol = (tid & 3) << 2;    // 0,4,8,12

    float acc[4][4] = {{0.f,0.f,0.f,0.f},{0.f,0.f,0.f,0.f},
                       {0.f,0.f,0.f,0.f},{0.f,0.f,0.f,0.f}};

    const float* aptr = A + (size_t)(rowBase + lrow) * EMB + lcol;
    const float* bptr = W + (size_t)(colBase + lrow) * EMB + lcol;

    for (int k0 = 0; k0 < EMB; k0 += 16) {
        float4 ar = *reinterpret_cast<const float4*>(aptr + k0);
        float4 br = *reinterpret_cast<const float4*>(bptr + k0);
        As[lrow][lcol + 0] = ar.x;
        As[lrow][lcol + 1] = ar.y;
        As[lrow][lcol + 2] = ar.z;
        As[lrow][lcol + 3] = ar.w;
        Bs[lrow][lcol + 0] = br.x;
        Bs[lrow][lcol + 1] = br.y;
        Bs[lrow][lcol + 2] = br.z;
        Bs[lrow][lcol + 3] = br.w;
        __syncthreads();

        #pragma unroll
        for (int kk = 0; kk < 16; ++kk) {
            float a0 = As[ty * 4 + 0][kk];
            float a1 = As[ty * 4 + 1][kk];
            float a2 = As[ty * 4 + 2][kk];
            float a3 = As[ty * 4 + 3][kk];
            float b0 = Bs[tx * 4 + 0][kk];
            float b1 = Bs[tx * 4 + 1][kk];
            float b2 = Bs[tx * 4 + 2][kk];
            float b3 = Bs[tx * 4 + 3][kk];
            acc[0][0] += a0 * b0; acc[0][1] += a0 * b1; acc[0][2] += a0 * b2; acc[0][3] += a0 * b3;
            acc[1][0] += a1 * b0; acc[1][1] += a1 * b1; acc[1][2] += a1 * b2; acc[1][3] += a1 * b3;
            acc[2][0] += a2 * b0; acc[2][1] += a2 * b1; acc[2][2] += a2 * b2; acc[2][3] += a2 * b3;
            acc[3][0] += a3 * b0; acc[3][1] += a3 * b1; acc[3][2] += a3 * b2; acc[3][3] += a3 * b3;
        }
        __syncthreads();
    }

    #pragma unroll
    for (int i = 0; i < 4; ++i) {
        const int r = rowBase + ty * 4 + i;
        const int srow = r >> 1;     // r = s*B + b, B=2
        const int bb = r & 1;
        #pragma unroll
        for (int j = 0; j < 4; ++j) {
            const int n = colBase + tx * 4 + j;
            const float c = (acc[i][j] + bv[n]) * scale;
            const int h = n >> 6;    // n = h*64 + d
            const int d = n & 63;
            out[(((size_t)(bb * NHEAD + h) * S_LEN + srow) << 6) + d] = c;
        }
    }
}

// ---------------------------------------------------------------------------
// Flash-style banded attention.
// One 256-thread block per (b*H+h, 64-query tile). K/V in 64-key LDS chunks.
// Scores + PV as 4x4-per-thread register GEMMs; online softmax with
// width-16 shuffle reductions (rows of a ty-group live in 16 adjacent lanes).
// q/k/v: [B,H,S,D] f32 (q pre-scaled). ctx out: [S,B,E] f32.
// ---------------------------------------------------------------------------
__global__ __launch_bounds__(256)
void attn_tile_kernel(const float* __restrict__ q,
                      const float* __restrict__ k,
                      const float* __restrict__ v,
                      float* __restrict__ ctx)
{
    __shared__ float Qs[64][65];
    __shared__ float KP[64][65];   // K chunk; reused as P buffer
    __shared__ float Vs[64][65];

    const int bh  = blockIdx.y;          // b*NHEAD + h
    const int s0  = blockIdx.x * 64;
    const int tid = threadIdx.x;
    const int tx  = tid & 15;
    const int ty  = tid >> 4;

    const size_t base = ((size_t)bh * S_LEN) << 6;   // * HDIM

    // Load Q tile (rows s0..s0+63, 64 cols): 16 floats per thread, coalesced.
    {
        const int row = tid >> 2;
        const int col = (tid & 3) << 4;
        const float* src = q + base + ((size_t)(s0 + row) << 6) + col;
        #pragma unroll
        for (int c = 0; c < 4; ++c) {
            float4 t = *reinterpret_cast<const float4*>(src + c * 4);
            Qs[row][col + c * 4 + 0] = t.x;
            Qs[row][col + c * 4 + 1] = t.y;
            Qs[row][col + c * 4 + 2] = t.z;
            Qs[row][col + c * 4 + 3] = t.w;
        }
    }

    float m_[4], l_[4], o_[4][4];
    #pragma unroll
    for (int i = 0; i < 4; ++i) {
        m_[i] = -1.0e30f;
        l_[i] = 0.f;
        #pragma unroll
        for (int j = 0; j < 4; ++j) o_[i][j] = 0.f;
    }

    int c0 = s0 - 128; if (c0 < 0) c0 = 0;
    int c1 = s0 + 192; if (c1 > S_LEN) c1 = S_LEN;

    for (int cb = c0; cb < c1; cb += 64) {
        __syncthreads();   // previous chunk's readers done (also covers Qs fill)

        // Load K and V chunks (64x64 each).
        {
            const int row = tid >> 2;
            const int col = (tid & 3) << 4;
            const float* ksrc = k + base + ((size_t)(cb + row) << 6) + col;
            const float* vsrc = v + base + ((size_t)(cb + row) << 6) + col;
            #pragma unroll
            for (int c = 0; c < 4; ++c) {
                float4 tk = *reinterpret_cast<const float4*>(ksrc + c * 4);
                float4 tv = *reinterpret_cast<const float4*>(vsrc + c * 4);
                KP[row][col + c * 4 + 0] = tk.x;
                KP[row][col + c * 4 + 1] = tk.y;
                KP[row][col + c * 4 + 2] = tk.z;
                KP[row][col + c * 4 + 3] = tk.w;
                Vs[row][col + c * 4 + 0] = tv.x;
                Vs[row][col + c * 4 + 1] = tv.y;
                Vs[row][col + c * 4 + 2] = tv.z;
                Vs[row][col + c * 4 + 3] = tv.w;
            }
        }
        __syncthreads();

        // S-tile = Q @ K^T (4x4 per thread).
        float sc[4][4] = {{0.f,0.f,0.f,0.f},{0.f,0.f,0.f,0.f},
                          {0.f,0.f,0.f,0.f},{0.f,0.f,0.f,0.f}};
        #pragma unroll 8
        for (int d = 0; d < 64; ++d) {
            float a0 = Qs[ty * 4 + 0][d];
            float a1 = Qs[ty * 4 + 1][d];
            float a2 = Qs[ty * 4 + 2][d];
            float a3 = Qs[ty * 4 + 3][d];
            float b0 = KP[tx * 4 + 0][d];
            float b1 = KP[tx * 4 + 1][d];
            float b2 = KP[tx * 4 + 2][d];
            float b3 = KP[tx * 4 + 3][d];
            sc[0][0] += a0 * b0; sc[0][1] += a0 * b1; sc[0][2] += a0 * b2; sc[0][3] += a0 * b3;
            sc[1][0] += a1 * b0; sc[1][1] += a1 * b1; sc[1][2] += a1 * b2; sc[1][3] += a1 * b3;
            sc[2][0] += a2 * b0; sc[2][1] += a2 * b1; sc[2][2] += a2 * b2; sc[2][3] += a2 * b3;
            sc[3][0] += a3 * b0; sc[3][1] += a3 * b1; sc[3][2] += a3 * b2; sc[3][3] += a3 * b3;
        }

        // Band mask: allowed iff i-128 <= j <= i+127.
        #pragma unroll
        for (int i = 0; i < 4; ++i) {
            const int ig = s0 + ty * 4 + i;
            #pragma unroll
            for (int j = 0; j < 4; ++j) {
                const int jg = cb + tx * 4 + j;
                if (jg < ig - 128 || jg >= ig + 128) sc[i][j] = -3.0e38f;
            }
        }

        // Online softmax per row (row-group = 16 adjacent lanes).
        #pragma unroll
        for (int i = 0; i < 4; ++i) {
            float rm = fmaxf(fmaxf(sc[i][0], sc[i][1]), fmaxf(sc[i][2], sc[i][3]));
            rm = fmaxf(rm, __shfl_xor(rm, 1));
            rm = fmaxf(rm, __shfl_xor(rm, 2));
            rm = fmaxf(rm, __shfl_xor(rm, 4));
            rm = fmaxf(rm, __shfl_xor(rm, 8));
            const float mn = fmaxf(m_[i], rm);
            const float alpha = __expf(m_[i] - mn);
            float rs = 0.f;
            #pragma unroll
            for (int j = 0; j < 4; ++j) {
                sc[i][j] = __expf(sc[i][j] - mn);
                rs += sc[i][j];
            }
            rs += __shfl_xor(rs, 1);
            rs += __shfl_xor(rs, 2);
            rs += __shfl_xor(rs, 4);
            rs += __shfl_xor(rs, 8);
            l_[i] = l_[i] * alpha + rs;
            m_[i] = mn;
            #pragma unroll
            for (int j = 0; j < 4; ++j) o_[i][j] *= alpha;
        }

        __syncthreads();   // all score reads of KP done
        #pragma unroll
        for (int i = 0; i < 4; ++i)
            #pragma unroll
            for (int j = 0; j < 4; ++j)
                KP[ty * 4 + i][tx * 4 + j] = sc[i][j];
        __syncthreads();

        // O += P @ V (4x4 per thread; cols are d-dims).
        #pragma unroll 8
        for (int kk = 0; kk < 64; ++kk) {
            float a0 = KP[ty * 4 + 0][kk];
            float a1 = KP[ty * 4 + 1][kk];
            float a2 = KP[ty * 4 + 2][kk];
            float a3 = KP[ty * 4 + 3][kk];
            float b0 = Vs[kk][tx * 4 + 0];
            float b1 = Vs[kk][tx * 4 + 1];
            float b2 = Vs[kk][tx * 4 + 2];
            float b3 = Vs[kk][tx * 4 + 3];
            o_[0][0] += a0 * b0; o_[0][1] += a0 * b1; o_[0][2] += a0 * b2; o_[0][3] += a0 * b3;
            o_[1][0] += a1 * b0; o_[1][1] += a1 * b1; o_[1][2] += a1 * b2; o_[1][3] += a1 * b3;
            o_[2][0] += a2 * b0; o_[2][1] += a2 * b1; o_[2][2] += a2 * b2; o_[2][3] += a2 * b3;
            o_[3][0] += a3 * b0; o_[3][1] += a3 * b1; o_[3][2] += a3 * b2; o_[3][3] += a3 * b3;
        }
    }

    // Epilogue: O/l -> ctx [S,B,E]
    const int b = bh >> 4;
    const int h = bh & 15;
    #pragma unroll
    for (int i = 0; i < 4; ++i) {
        const int ig = s0 + ty * 4 + i;
        const float inv = 1.0f / l_[i];
        float4 r;
        r.x = o_[i][0] * inv;
        r.y = o_[i][1] * inv;
        r.z = o_[i][2] * inv;
        r.w = o_[i][3] * inv;
        *reinterpret_cast<float4*>(
            &ctx[((size_t)(ig * BATCH + b) << 10) + (h << 6) + (tx << 2)]) = r;
    }
}

// ---------------------------------------------------------------------------
// Output projection: out[r,n] = sum_k ctx[r,k] * W[n,k] + bias[n] -> f32
// ---------------------------------------------------------------------------
__global__ __launch_bounds__(256)
void out_gemm_kernel(const float* __restrict__ ctx,
                     const float* __restrict__ w,
                     const float* __restrict__ bias,
                     float* __restrict__ out)
{
    __shared__ float As[64][17];
    __shared__ float Bs[64][17];

    const int tid = threadIdx.x;
    const int tx = tid & 15;
    const int ty = tid >> 4;
    const int rowBase = blockIdx.y * 64;
    const int colBase = blockIdx.x * 64;

    const int lrow = tid >> 2;
    const int lcol = (tid & 3) << 2;

    float acc[4][4] = {{0.f,0.f,0.f,0.f},{0.f,0.f,0.f,0.f},
                       {0.f,0.f,0.f,0.f},{0.f,0.f,0.f,0.f}};

    const float* aptr = ctx + (size_t)(rowBase + lrow) * EMB + lcol;
    const float* bptr = w + (size_t)(colBase + lrow) * EMB + lcol;

    for (int k0 = 0; k0 < EMB; k0 += 16) {
        float4 ar = *reinterpret_cast<const float4*>(aptr + k0);
        float4 br = *reinterpret_cast<const float4*>(bptr + k0);
        As[lrow][lcol + 0] = ar.x;
        As[lrow][lcol + 1] = ar.y;
        As[lrow][lcol + 2] = ar.z;
        As[lrow][lcol + 3] = ar.w;
        Bs[lrow][lcol + 0] = br.x;
        Bs[lrow][lcol + 1] = br.y;
        Bs[lrow][lcol + 2] = br.z;
        Bs[lrow][lcol + 3] = br.w;
        __syncthreads();

        #pragma unroll
        for (int kk = 0; kk < 16; ++kk) {
            float a0 = As[ty * 4 + 0][kk];
            float a1 = As[ty * 4 + 1][kk];
            float a2 = As[ty * 4 + 2][kk];
            float a3 = As[ty * 4 + 3][kk];
            float b0 = Bs[tx * 4 + 0][kk];
            float b1 = Bs[tx * 4 + 1][kk];
            float b2 = Bs[tx * 4 + 2][kk];
            float b3 = Bs[tx * 4 + 3][kk];
            acc[0][0] += a0 * b0; acc[0][1] += a0 * b1; acc[0][2] += a0 * b2; acc[0][3] += a0 * b3;
            acc[1][0] += a1 * b0; acc[1][1] += a1 * b1; acc[1][2] += a1 * b2; acc[1][3] += a1 * b3;
            acc[2][0] += a2 * b0; acc[2][1] += a2 * b1; acc[2][2] += a2 * b2; acc[2][3] += a2 * b3;
            acc[3][0] += a3 * b0; acc[3][1] += a3 * b1; acc[3][2] += a3 * b2; acc[3][3] += a3 * b3;
        }
        __syncthreads();
    }

    #pragma unroll
    for (int i = 0; i < 4; ++i) {
        const int r = rowBase + ty * 4 + i;
        #pragma unroll
        for (int j = 0; j < 4; ++j) {
            const int n = colBase + tx * 4 + j;
            out[(size_t)r * EMB + n] = acc[i][j] + bias[n];
        }
    }
}

// ---------------------------------------------------------------------------
extern "C" void kernel_launch(void* const* d_in, const int* in_sizes, int n_in,
                              void* d_out, int out_size, void* d_ws, size_t ws_size,
                              hipStream_t stream) {
    const float* query = (const float*)d_in[0];
    const float* key   = (const float*)d_in[1];
    const float* value = (const float*)d_in[2];
    const float* in_w  = (const float*)d_in[3];
    const float* in_b  = (const float*)d_in[4];
    const float* out_w = (const float*)d_in[5];
    const float* out_b = (const float*)d_in[6];
    // d_in[7] = num_heads (16), d_in[8] = block_size (128): baked as constants.

    // Workspace: q,k,v [B,H,S,D] f32 + ctx [S*B,E] f32 = 4 * 16 MB = 64 MB
    const size_t PLANE = (size_t)BATCH * NHEAD * S_LEN * HDIM;  // 4194304
    float* qw = (float*)d_ws;
    float* kw = qw + PLANE;
    float* vw = kw + PLANE;
    float* cw = vw + PLANE;

    dim3 g1(EMB / 64, (S_LEN * BATCH) / 64, 3);
    qkv_gemm_kernel<<<g1, 256, 0, stream>>>(query, key, value, in_w, in_b, qw, kw, vw);

    dim3 g2(S_LEN / 64, BATCH * NHEAD);
    attn_tile_kernel<<<g2, 256, 0, stream>>>(qw, kw, vw, cw);

    dim3 g3(EMB / 64, (S_LEN * BATCH) / 64);
    out_gemm_kernel<<<g3, 256, 0, stream>>>(cw, out_w, out_b, (float*)d_out);
}

// Round 4
// 386.839 us; speedup vs baseline: 4.7130x; 2.3329x over previous
//
#include <hip/hip_runtime.h>
#include <hip/hip_bf16.h>

// Problem constants (setup_inputs is fixed)
#define S_LEN 2048
#define BATCH 2
#define EMB   1024
#define NHEAD 16
#define HDIM  64
#define WIN   128

typedef __attribute__((ext_vector_type(8))) short short8;
typedef __attribute__((ext_vector_type(4))) float floatx4;

// Pack two f32 into two RNE-rounded bf16 (lo = a, hi = b).
__device__ __forceinline__ unsigned int pk2bf(float a, float b) {
    unsigned int ua = __builtin_bit_cast(unsigned int, a);
    unsigned int ub = __builtin_bit_cast(unsigned int, b);
    ua += 0x7fffu + ((ua >> 16) & 1u);
    ub += 0x7fffu + ((ub >> 16) & 1u);
    return (ua >> 16) | (ub & 0xffff0000u);
}

#define LDS_STRIDE 40  // ushorts per 32-k row; 80B keeps 16B align, spreads banks

// ---------------------------------------------------------------------------
// QKV projection via bf16 MFMA: Y[m,n] = sum_k X[m,k]*W[n,k] + bias[n]
// X: [4096, 1024] f32 (one of q/k/v by blockIdx.z). W slice [1024,1024] f32.
// Out: [B,H,S,D] f32, q scaled by 0.125. 128x128 tile, BK=32, 256 thr.
// ---------------------------------------------------------------------------
__global__ __launch_bounds__(256)
void qkv_mfma_kernel(const float* __restrict__ xq,
                     const float* __restrict__ xk,
                     const float* __restrict__ xv,
                     const float* __restrict__ w,     // [3E, E]
                     const float* __restrict__ bias,  // [3E]
                     float* __restrict__ qw,
                     float* __restrict__ kw,
                     float* __restrict__ vw)
{
    __shared__ unsigned short Asb[128 * LDS_STRIDE];
    __shared__ unsigned short Bsb[128 * LDS_STRIDE];

    const int which = blockIdx.z;
    const float* A  = (which == 0) ? xq : (which == 1) ? xk : xv;
    const float* W  = w + (size_t)which * EMB * EMB;
    const float* bv = bias + which * EMB;
    float* out = (which == 0) ? qw : (which == 1) ? kw : vw;
    const float scale = (which == 0) ? 0.125f : 1.0f;

    const int tid   = threadIdx.x;
    const int lane  = tid & 63;
    const int wave  = tid >> 6;
    const int quad  = lane >> 4;
    const int c16   = lane & 15;
    const int wm    = (wave & 1) << 6;   // wave m-offset in tile
    const int wn    = (wave >> 1) << 6;  // wave n-offset in tile

    const int rowBase = blockIdx.y * 128;   // M (= s*B+b rows)
    const int colBase = blockIdx.x * 128;   // N (weight rows)

    // Staging assignment: thread -> (row r=tid>>1, 16 k-cols at cs)
    const int sr = tid >> 1;
    const int cs = (tid & 1) << 4;
    const float* asrc = A + (size_t)(rowBase + sr) * EMB + cs;
    const float* bsrc = W + (size_t)(colBase + sr) * EMB + cs;
    unsigned short* awr = &Asb[sr * LDS_STRIDE + cs];
    unsigned short* bwr = &Bsb[sr * LDS_STRIDE + cs];

    floatx4 acc[4][4];
    #pragma unroll
    for (int i = 0; i < 4; ++i)
        #pragma unroll
        for (int j = 0; j < 4; ++j)
            acc[i][j] = (floatx4){0.f, 0.f, 0.f, 0.f};

    for (int k0 = 0; k0 < EMB; k0 += 32) {
        __syncthreads();
        {
            float4 a0 = *reinterpret_cast<const float4*>(asrc + k0);
            float4 a1 = *reinterpret_cast<const float4*>(asrc + k0 + 4);
            float4 a2 = *reinterpret_cast<const float4*>(asrc + k0 + 8);
            float4 a3 = *reinterpret_cast<const float4*>(asrc + k0 + 12);
            float4 b0 = *reinterpret_cast<const float4*>(bsrc + k0);
            float4 b1 = *reinterpret_cast<const float4*>(bsrc + k0 + 4);
            float4 b2 = *reinterpret_cast<const float4*>(bsrc + k0 + 8);
            float4 b3 = *reinterpret_cast<const float4*>(bsrc + k0 + 12);
            uint4 pa0 = {pk2bf(a0.x,a0.y), pk2bf(a0.z,a0.w), pk2bf(a1.x,a1.y), pk2bf(a1.z,a1.w)};
            uint4 pa1 = {pk2bf(a2.x,a2.y), pk2bf(a2.z,a2.w), pk2bf(a3.x,a3.y), pk2bf(a3.z,a3.w)};
            uint4 pb0 = {pk2bf(b0.x,b0.y), pk2bf(b0.z,b0.w), pk2bf(b1.x,b1.y), pk2bf(b1.z,b1.w)};
            uint4 pb1 = {pk2bf(b2.x,b2.y), pk2bf(b2.z,b2.w), pk2bf(b3.x,b3.y), pk2bf(b3.z,b3.w)};
            *reinterpret_cast<uint4*>(awr)     = pa0;
            *reinterpret_cast<uint4*>(awr + 8) = pa1;
            *reinterpret_cast<uint4*>(bwr)     = pb0;
            *reinterpret_cast<uint4*>(bwr + 8) = pb1;
        }
        __syncthreads();

        short8 af[4], bf[4];
        #pragma unroll
        for (int mi = 0; mi < 4; ++mi)
            af[mi] = *reinterpret_cast<const short8*>(
                &Asb[(wm + mi * 16 + c16) * LDS_STRIDE + quad * 8]);
        #pragma unroll
        for (int ni = 0; ni < 4; ++ni)
            bf[ni] = *reinterpret_cast<const short8*>(
                &Bsb[(wn + ni * 16 + c16) * LDS_STRIDE + quad * 8]);

        #pragma unroll
        for (int mi = 0; mi < 4; ++mi)
            #pragma unroll
            for (int ni = 0; ni < 4; ++ni)
                acc[mi][ni] = __builtin_amdgcn_mfma_f32_16x16x32_bf16(
                    af[mi], bf[ni], acc[mi][ni], 0, 0, 0);
    }

    // Epilogue: D[m = quad*4+r][n = c16] per 16x16 tile.
    #pragma unroll
    for (int ni = 0; ni < 4; ++ni) {
        const int n_full = colBase + wn + ni * 16 + c16;   // 0..1023
        const float bb = bv[n_full];
        const int h = n_full >> 6;
        const int d = n_full & 63;
        #pragma unroll
        for (int mi = 0; mi < 4; ++mi) {
            #pragma unroll
            for (int r = 0; r < 4; ++r) {
                const int m_g = rowBase + wm + mi * 16 + quad * 4 + r;
                const int s   = m_g >> 1;      // m = s*B + b
                const int b   = m_g & 1;
                const float val = (acc[mi][ni][r] + bb) * scale;
                out[(((size_t)(b * NHEAD + h) * S_LEN + s) << 6) + d] = val;
            }
        }
    }
}

// ---------------------------------------------------------------------------
// Output projection via bf16 MFMA: out[m,n] = sum_k ctx[m,k]*W[n,k] + bias[n]
// ctx: [4096,1024] f32 ([S,B,E] row = s*B+b). out: same layout f32.
// ---------------------------------------------------------------------------
__global__ __launch_bounds__(256)
void out_mfma_kernel(const float* __restrict__ ctx,
                     const float* __restrict__ w,
                     const float* __restrict__ bias,
                     float* __restrict__ out)
{
    __shared__ unsigned short Asb[128 * LDS_STRIDE];
    __shared__ unsigned short Bsb[128 * LDS_STRIDE];

    const int tid   = threadIdx.x;
    const int lane  = tid & 63;
    const int wave  = tid >> 6;
    const int quad  = lane >> 4;
    const int c16   = lane & 15;
    const int wm    = (wave & 1) << 6;
    const int wn    = (wave >> 1) << 6;

    const int rowBase = blockIdx.y * 128;
    const int colBase = blockIdx.x * 128;

    const int sr = tid >> 1;
    const int cs = (tid & 1) << 4;
    const float* asrc = ctx + (size_t)(rowBase + sr) * EMB + cs;
    const float* bsrc = w   + (size_t)(colBase + sr) * EMB + cs;
    unsigned short* awr = &Asb[sr * LDS_STRIDE + cs];
    unsigned short* bwr = &Bsb[sr * LDS_STRIDE + cs];

    floatx4 acc[4][4];
    #pragma unroll
    for (int i = 0; i < 4; ++i)
        #pragma unroll
        for (int j = 0; j < 4; ++j)
            acc[i][j] = (floatx4){0.f, 0.f, 0.f, 0.f};

    for (int k0 = 0; k0 < EMB; k0 += 32) {
        __syncthreads();
        {
            float4 a0 = *reinterpret_cast<const float4*>(asrc + k0);
            float4 a1 = *reinterpret_cast<const float4*>(asrc + k0 + 4);
            float4 a2 = *reinterpret_cast<const float4*>(asrc + k0 + 8);
            float4 a3 = *reinterpret_cast<const float4*>(asrc + k0 + 12);
            float4 b0 = *reinterpret_cast<const float4*>(bsrc + k0);
            float4 b1 = *reinterpret_cast<const float4*>(bsrc + k0 + 4);
            float4 b2 = *reinterpret_cast<const float4*>(bsrc + k0 + 8);
            float4 b3 = *reinterpret_cast<const float4*>(bsrc + k0 + 12);
            uint4 pa0 = {pk2bf(a0.x,a0.y), pk2bf(a0.z,a0.w), pk2bf(a1.x,a1.y), pk2bf(a1.z,a1.w)};
            uint4 pa1 = {pk2bf(a2.x,a2.y), pk2bf(a2.z,a2.w), pk2bf(a3.x,a3.y), pk2bf(a3.z,a3.w)};
            uint4 pb0 = {pk2bf(b0.x,b0.y), pk2bf(b0.z,b0.w), pk2bf(b1.x,b1.y), pk2bf(b1.z,b1.w)};
            uint4 pb1 = {pk2bf(b2.x,b2.y), pk2bf(b2.z,b2.w), pk2bf(b3.x,b3.y), pk2bf(b3.z,b3.w)};
            *reinterpret_cast<uint4*>(awr)     = pa0;
            *reinterpret_cast<uint4*>(awr + 8) = pa1;
            *reinterpret_cast<uint4*>(bwr)     = pb0;
            *reinterpret_cast<uint4*>(bwr + 8) = pb1;
        }
        __syncthreads();

        short8 af[4], bf[4];
        #pragma unroll
        for (int mi = 0; mi < 4; ++mi)
            af[mi] = *reinterpret_cast<const short8*>(
                &Asb[(wm + mi * 16 + c16) * LDS_STRIDE + quad * 8]);
        #pragma unroll
        for (int ni = 0; ni < 4; ++ni)
            bf[ni] = *reinterpret_cast<const short8*>(
                &Bsb[(wn + ni * 16 + c16) * LDS_STRIDE + quad * 8]);

        #pragma unroll
        for (int mi = 0; mi < 4; ++mi)
            #pragma unroll
            for (int ni = 0; ni < 4; ++ni)
                acc[mi][ni] = __builtin_amdgcn_mfma_f32_16x16x32_bf16(
                    af[mi], bf[ni], acc[mi][ni], 0, 0, 0);
    }

    #pragma unroll
    for (int ni = 0; ni < 4; ++ni) {
        const int n_full = colBase + wn + ni * 16 + c16;
        const float bb = bias[n_full];
        #pragma unroll
        for (int mi = 0; mi < 4; ++mi) {
            #pragma unroll
            for (int r = 0; r < 4; ++r) {
                const int m_g = rowBase + wm + mi * 16 + quad * 4 + r;
                out[(size_t)m_g * EMB + n_full] = acc[mi][ni][r] + bb;
            }
        }
    }
}

// ---------------------------------------------------------------------------
// Flash-style banded attention (unchanged from round 3).
// q/k/v: [B,H,S,D] f32 (q pre-scaled). ctx out: [S,B,E] f32.
// ---------------------------------------------------------------------------
__global__ __launch_bounds__(256)
void attn_tile_kernel(const float* __restrict__ q,
                      const float* __restrict__ k,
                      const float* __restrict__ v,
                      float* __restrict__ ctx)
{
    __shared__ float Qs[64][65];
    __shared__ float KP[64][65];   // K chunk; reused as P buffer
    __shared__ float Vs[64][65];

    const int bh  = blockIdx.y;
    const int s0  = blockIdx.x * 64;
    const int tid = threadIdx.x;
    const int tx  = tid & 15;
    const int ty  = tid >> 4;

    const size_t base = ((size_t)bh * S_LEN) << 6;

    {
        const int row = tid >> 2;
        const int col = (tid & 3) << 4;
        const float* src = q + base + ((size_t)(s0 + row) << 6) + col;
        #pragma unroll
        for (int c = 0; c < 4; ++c) {
            float4 t = *reinterpret_cast<const float4*>(src + c * 4);
            Qs[row][col + c * 4 + 0] = t.x;
            Qs[row][col + c * 4 + 1] = t.y;
            Qs[row][col + c * 4 + 2] = t.z;
            Qs[row][col + c * 4 + 3] = t.w;
        }
    }

    float m_[4], l_[4], o_[4][4];
    #pragma unroll
    for (int i = 0; i < 4; ++i) {
        m_[i] = -1.0e30f;
        l_[i] = 0.f;
        #pragma unroll
        for (int j = 0; j < 4; ++j) o_[i][j] = 0.f;
    }

    int c0 = s0 - 128; if (c0 < 0) c0 = 0;
    int c1 = s0 + 192; if (c1 > S_LEN) c1 = S_LEN;

    for (int cb = c0; cb < c1; cb += 64) {
        __syncthreads();

        {
            const int row = tid >> 2;
            const int col = (tid & 3) << 4;
            const float* ksrc = k + base + ((size_t)(cb + row) << 6) + col;
            const float* vsrc = v + base + ((size_t)(cb + row) << 6) + col;
            #pragma unroll
            for (int c = 0; c < 4; ++c) {
                float4 tk = *reinterpret_cast<const float4*>(ksrc + c * 4);
                float4 tv = *reinterpret_cast<const float4*>(vsrc + c * 4);
                KP[row][col + c * 4 + 0] = tk.x;
                KP[row][col + c * 4 + 1] = tk.y;
                KP[row][col + c * 4 + 2] = tk.z;
                KP[row][col + c * 4 + 3] = tk.w;
                Vs[row][col + c * 4 + 0] = tv.x;
                Vs[row][col + c * 4 + 1] = tv.y;
                Vs[row][col + c * 4 + 2] = tv.z;
                Vs[row][col + c * 4 + 3] = tv.w;
            }
        }
        __syncthreads();

        float sc[4][4] = {{0.f,0.f,0.f,0.f},{0.f,0.f,0.f,0.f},
                          {0.f,0.f,0.f,0.f},{0.f,0.f,0.f,0.f}};
        #pragma unroll 8
        for (int d = 0; d < 64; ++d) {
            float a0 = Qs[ty * 4 + 0][d];
            float a1 = Qs[ty * 4 + 1][d];
            float a2 = Qs[ty * 4 + 2][d];
            float a3 = Qs[ty * 4 + 3][d];
            float b0 = KP[tx * 4 + 0][d];
            float b1 = KP[tx * 4 + 1][d];
            float b2 = KP[tx * 4 + 2][d];
            float b3 = KP[tx * 4 + 3][d];
            sc[0][0] += a0 * b0; sc[0][1] += a0 * b1; sc[0][2] += a0 * b2; sc[0][3] += a0 * b3;
            sc[1][0] += a1 * b0; sc[1][1] += a1 * b1; sc[1][2] += a1 * b2; sc[1][3] += a1 * b3;
            sc[2][0] += a2 * b0; sc[2][1] += a2 * b1; sc[2][2] += a2 * b2; sc[2][3] += a2 * b3;
            sc[3][0] += a3 * b0; sc[3][1] += a3 * b1; sc[3][2] += a3 * b2; sc[3][3] += a3 * b3;
        }

        #pragma unroll
        for (int i = 0; i < 4; ++i) {
            const int ig = s0 + ty * 4 + i;
            #pragma unroll
            for (int j = 0; j < 4; ++j) {
                const int jg = cb + tx * 4 + j;
                if (jg < ig - 128 || jg >= ig + 128) sc[i][j] = -3.0e38f;
            }
        }

        #pragma unroll
        for (int i = 0; i < 4; ++i) {
            float rm = fmaxf(fmaxf(sc[i][0], sc[i][1]), fmaxf(sc[i][2], sc[i][3]));
            rm = fmaxf(rm, __shfl_xor(rm, 1));
            rm = fmaxf(rm, __shfl_xor(rm, 2));
            rm = fmaxf(rm, __shfl_xor(rm, 4));
            rm = fmaxf(rm, __shfl_xor(rm, 8));
            const float mn = fmaxf(m_[i], rm);
            const float alpha = __expf(m_[i] - mn);
            float rs = 0.f;
            #pragma unroll
            for (int j = 0; j < 4; ++j) {
                sc[i][j] = __expf(sc[i][j] - mn);
                rs += sc[i][j];
            }
            rs += __shfl_xor(rs, 1);
            rs += __shfl_xor(rs, 2);
            rs += __shfl_xor(rs, 4);
            rs += __shfl_xor(rs, 8);
            l_[i] = l_[i] * alpha + rs;
            m_[i] = mn;
            #pragma unroll
            for (int j = 0; j < 4; ++j) o_[i][j] *= alpha;
        }

        __syncthreads();
        #pragma unroll
        for (int i = 0; i < 4; ++i)
            #pragma unroll
            for (int j = 0; j < 4; ++j)
                KP[ty * 4 + i][tx * 4 + j] = sc[i][j];
        __syncthreads();

        #pragma unroll 8
        for (int kk = 0; kk < 64; ++kk) {
            float a0 = KP[ty * 4 + 0][kk];
            float a1 = KP[ty * 4 + 1][kk];
            float a2 = KP[ty * 4 + 2][kk];
            float a3 = KP[ty * 4 + 3][kk];
            float b0 = Vs[kk][tx * 4 + 0];
            float b1 = Vs[kk][tx * 4 + 1];
            float b2 = Vs[kk][tx * 4 + 2];
            float b3 = Vs[kk][tx * 4 + 3];
            o_[0][0] += a0 * b0; o_[0][1] += a0 * b1; o_[0][2] += a0 * b2; o_[0][3] += a0 * b3;
            o_[1][0] += a1 * b0; o_[1][1] += a1 * b1; o_[1][2] += a1 * b2; o_[1][3] += a1 * b3;
            o_[2][0] += a2 * b0; o_[2][1] += a2 * b1; o_[2][2] += a2 * b2; o_[2][3] += a2 * b3;
            o_[3][0] += a3 * b0; o_[3][1] += a3 * b1; o_[3][2] += a3 * b2; o_[3][3] += a3 * b3;
        }
    }

    const int b = bh >> 4;
    const int h = bh & 15;
    #pragma unroll
    for (int i = 0; i < 4; ++i) {
        const int ig = s0 + ty * 4 + i;
        const float inv = 1.0f / l_[i];
        float4 r;
        r.x = o_[i][0] * inv;
        r.y = o_[i][1] * inv;
        r.z = o_[i][2] * inv;
        r.w = o_[i][3] * inv;
        *reinterpret_cast<float4*>(
            &ctx[((size_t)(ig * BATCH + b) << 10) + (h << 6) + (tx << 2)]) = r;
    }
}

// ---------------------------------------------------------------------------
extern "C" void kernel_launch(void* const* d_in, const int* in_sizes, int n_in,
                              void* d_out, int out_size, void* d_ws, size_t ws_size,
                              hipStream_t stream) {
    const float* query = (const float*)d_in[0];
    const float* key   = (const float*)d_in[1];
    const float* value = (const float*)d_in[2];
    const float* in_w  = (const float*)d_in[3];
    const float* in_b  = (const float*)d_in[4];
    const float* out_w = (const float*)d_in[5];
    const float* out_b = (const float*)d_in[6];

    const size_t PLANE = (size_t)BATCH * NHEAD * S_LEN * HDIM;  // 4194304
    float* qw = (float*)d_ws;
    float* kw = qw + PLANE;
    float* vw = kw + PLANE;
    float* cw = vw + PLANE;

    dim3 g1(EMB / 128, (S_LEN * BATCH) / 128, 3);
    qkv_mfma_kernel<<<g1, 256, 0, stream>>>(query, key, value, in_w, in_b, qw, kw, vw);

    dim3 g2(S_LEN / 64, BATCH * NHEAD);
    attn_tile_kernel<<<g2, 256, 0, stream>>>(qw, kw, vw, cw);

    dim3 g3(EMB / 128, (S_LEN * BATCH) / 128);
    out_mfma_kernel<<<g3, 256, 0, stream>>>(cw, out_w, out_b, (float*)d_out);
}

// Round 5
// 258.619 us; speedup vs baseline: 7.0497x; 1.4958x over previous
//
#include <hip/hip_runtime.h>
#include <hip/hip_bf16.h>

// Problem constants (setup_inputs is fixed)
#define S_LEN 2048
#define BATCH 2
#define EMB   1024
#define NHEAD 16
#define HDIM  64
#define WIN   128

typedef __attribute__((ext_vector_type(8))) short short8;
typedef __attribute__((ext_vector_type(4))) float floatx4;

// Pack two f32 into two RNE-rounded bf16 (lo = a, hi = b).
__device__ __forceinline__ unsigned int pk2bf(float a, float b) {
    unsigned int ua = __builtin_bit_cast(unsigned int, a);
    unsigned int ub = __builtin_bit_cast(unsigned int, b);
    ua += 0x7fffu + ((ua >> 16) & 1u);
    ub += 0x7fffu + ((ub >> 16) & 1u);
    return (ua >> 16) | (ub & 0xffff0000u);
}
__device__ __forceinline__ unsigned short f2bf(float f) {
    unsigned int u = __builtin_bit_cast(unsigned int, f);
    u += 0x7fffu + ((u >> 16) & 1u);
    return (unsigned short)(u >> 16);
}

#define LDS_STRIDE 40  // ushorts per 32-k row (GEMM staging)

// ---------------------------------------------------------------------------
// QKV projection via bf16 MFMA: Y[m,n] = sum_k X[m,k]*W[n,k] + bias[n]
// Outputs bf16: q,k as [B,H,S,D] (q scaled 0.125), v TRANSPOSED as [B,H,D,S].
// ---------------------------------------------------------------------------
__global__ __launch_bounds__(256)
void qkv_mfma_kernel(const float* __restrict__ xq,
                     const float* __restrict__ xk,
                     const float* __restrict__ xv,
                     const float* __restrict__ w,     // [3E, E]
                     const float* __restrict__ bias,  // [3E]
                     unsigned short* __restrict__ qo,
                     unsigned short* __restrict__ ko,
                     unsigned short* __restrict__ vto)
{
    __shared__ unsigned short Asb[128 * LDS_STRIDE];
    __shared__ unsigned short Bsb[128 * LDS_STRIDE];

    const int which = blockIdx.z;
    const float* A  = (which == 0) ? xq : (which == 1) ? xk : xv;
    const float* W  = w + (size_t)which * EMB * EMB;
    const float* bv = bias + which * EMB;
    const float scale = (which == 0) ? 0.125f : 1.0f;

    const int tid   = threadIdx.x;
    const int lane  = tid & 63;
    const int wave  = tid >> 6;
    const int quad  = lane >> 4;
    const int c16   = lane & 15;
    const int wm    = (wave & 1) << 6;
    const int wn    = (wave >> 1) << 6;

    const int rowBase = blockIdx.y * 128;   // M (= s*B+b rows)
    const int colBase = blockIdx.x * 128;   // N (weight rows)

    const int sr = tid >> 1;
    const int cs = (tid & 1) << 4;
    const float* asrc = A + (size_t)(rowBase + sr) * EMB + cs;
    const float* bsrc = W + (size_t)(colBase + sr) * EMB + cs;
    unsigned short* awr = &Asb[sr * LDS_STRIDE + cs];
    unsigned short* bwr = &Bsb[sr * LDS_STRIDE + cs];

    floatx4 acc[4][4];
    #pragma unroll
    for (int i = 0; i < 4; ++i)
        #pragma unroll
        for (int j = 0; j < 4; ++j)
            acc[i][j] = (floatx4){0.f, 0.f, 0.f, 0.f};

    for (int k0 = 0; k0 < EMB; k0 += 32) {
        __syncthreads();
        {
            float4 a0 = *reinterpret_cast<const float4*>(asrc + k0);
            float4 a1 = *reinterpret_cast<const float4*>(asrc + k0 + 4);
            float4 a2 = *reinterpret_cast<const float4*>(asrc + k0 + 8);
            float4 a3 = *reinterpret_cast<const float4*>(asrc + k0 + 12);
            float4 b0 = *reinterpret_cast<const float4*>(bsrc + k0);
            float4 b1 = *reinterpret_cast<const float4*>(bsrc + k0 + 4);
            float4 b2 = *reinterpret_cast<const float4*>(bsrc + k0 + 8);
            float4 b3 = *reinterpret_cast<const float4*>(bsrc + k0 + 12);
            uint4 pa0 = {pk2bf(a0.x,a0.y), pk2bf(a0.z,a0.w), pk2bf(a1.x,a1.y), pk2bf(a1.z,a1.w)};
            uint4 pa1 = {pk2bf(a2.x,a2.y), pk2bf(a2.z,a2.w), pk2bf(a3.x,a3.y), pk2bf(a3.z,a3.w)};
            uint4 pb0 = {pk2bf(b0.x,b0.y), pk2bf(b0.z,b0.w), pk2bf(b1.x,b1.y), pk2bf(b1.z,b1.w)};
            uint4 pb1 = {pk2bf(b2.x,b2.y), pk2bf(b2.z,b2.w), pk2bf(b3.x,b3.y), pk2bf(b3.z,b3.w)};
            *reinterpret_cast<uint4*>(awr)     = pa0;
            *reinterpret_cast<uint4*>(awr + 8) = pa1;
            *reinterpret_cast<uint4*>(bwr)     = pb0;
            *reinterpret_cast<uint4*>(bwr + 8) = pb1;
        }
        __syncthreads();

        short8 af[4], bf[4];
        #pragma unroll
        for (int mi = 0; mi < 4; ++mi)
            af[mi] = *reinterpret_cast<const short8*>(
                &Asb[(wm + mi * 16 + c16) * LDS_STRIDE + quad * 8]);
        #pragma unroll
        for (int ni = 0; ni < 4; ++ni)
            bf[ni] = *reinterpret_cast<const short8*>(
                &Bsb[(wn + ni * 16 + c16) * LDS_STRIDE + quad * 8]);

        #pragma unroll
        for (int mi = 0; mi < 4; ++mi)
            #pragma unroll
            for (int ni = 0; ni < 4; ++ni)
                acc[mi][ni] = __builtin_amdgcn_mfma_f32_16x16x32_bf16(
                    af[mi], bf[ni], acc[mi][ni], 0, 0, 0);
    }

    // Epilogue -> bf16. D[m = quad*4+r][n = c16] per 16x16 tile.
    #pragma unroll
    for (int ni = 0; ni < 4; ++ni) {
        const int n_full = colBase + wn + ni * 16 + c16;   // 0..1023
        const float bb = bv[n_full];
        const int h = n_full >> 6;
        const int d = n_full & 63;
        #pragma unroll
        for (int mi = 0; mi < 4; ++mi) {
            #pragma unroll
            for (int r = 0; r < 4; ++r) {
                const int m_g = rowBase + wm + mi * 16 + quad * 4 + r;
                const int s   = m_g >> 1;      // m = s*B + b
                const int b   = m_g & 1;
                const int bh  = b * NHEAD + h;
                const unsigned short val = f2bf((acc[mi][ni][r] + bb) * scale);
                if (which == 2)
                    vto[((size_t)bh * HDIM + d) * S_LEN + s] = val;
                else if (which == 0)
                    qo[((size_t)bh * S_LEN + s) * HDIM + d] = val;
                else
                    ko[((size_t)bh * S_LEN + s) * HDIM + d] = val;
            }
        }
    }
}

// ---------------------------------------------------------------------------
// MFMA flash attention over the band. One 256-thread block per (bh, 64-query
// tile); each wave owns 16 queries. K chunks of 64 keys. q/k: [B,H,S,D] bf16
// (q pre-scaled), vt: [B,H,D,S] bf16. ctx out: [S,B,E] f32.
// ---------------------------------------------------------------------------
#define AT_STRIDE 72   // ushorts per LDS row (144B, 16B-aligned)

__global__ __launch_bounds__(256)
void attn_mfma_kernel(const unsigned short* __restrict__ q,
                      const unsigned short* __restrict__ k,
                      const unsigned short* __restrict__ vt,
                      float* __restrict__ ctx)
{
    __shared__ unsigned short Qs[64 * AT_STRIDE];
    __shared__ unsigned short Ks[64 * AT_STRIDE];
    __shared__ unsigned short Vts[64 * AT_STRIDE];
    __shared__ unsigned short Ps[64 * AT_STRIDE];

    const int bh  = blockIdx.y;
    const int s0  = blockIdx.x * 64;
    const int tid = threadIdx.x;
    const int lane = tid & 63;
    const int wave = tid >> 6;
    const int quad = lane >> 4;
    const int c16  = lane & 15;

    const size_t base_qk = ((size_t)bh * S_LEN) * HDIM;
    const size_t base_vt = ((size_t)bh * HDIM) * S_LEN;

    // Stage Q tile: row = tid>>2 (0..63), 16 shorts at seg.
    const int srow = tid >> 2;
    const int sseg = (tid & 3) << 4;
    {
        const unsigned short* src = q + base_qk + (size_t)(s0 + srow) * HDIM + sseg;
        uint4 v0 = *reinterpret_cast<const uint4*>(src);
        uint4 v1 = *reinterpret_cast<const uint4*>(src + 8);
        *reinterpret_cast<uint4*>(&Qs[srow * AT_STRIDE + sseg])     = v0;
        *reinterpret_cast<uint4*>(&Qs[srow * AT_STRIDE + sseg + 8]) = v1;
    }

    float m_[4], l_[4];
    floatx4 ob[4];
    #pragma unroll
    for (int r = 0; r < 4; ++r) { m_[r] = -1.0e30f; l_[r] = 0.f; }
    #pragma unroll
    for (int dt = 0; dt < 4; ++dt) ob[dt] = (floatx4){0.f, 0.f, 0.f, 0.f};

    int c0 = s0 - 128; if (c0 < 0) c0 = 0;
    int c1 = s0 + 192; if (c1 > S_LEN) c1 = S_LEN;

    for (int cb = c0; cb < c1; cb += 64) {
        __syncthreads();   // previous chunk's K/Vt readers done (covers Q fill)
        {
            const unsigned short* ksrc = k + base_qk + (size_t)(cb + srow) * HDIM + sseg;
            const unsigned short* vsrc = vt + base_vt + (size_t)srow * S_LEN + cb + sseg;
            uint4 k0v = *reinterpret_cast<const uint4*>(ksrc);
            uint4 k1v = *reinterpret_cast<const uint4*>(ksrc + 8);
            uint4 v0v = *reinterpret_cast<const uint4*>(vsrc);
            uint4 v1v = *reinterpret_cast<const uint4*>(vsrc + 8);
            *reinterpret_cast<uint4*>(&Ks[srow * AT_STRIDE + sseg])      = k0v;
            *reinterpret_cast<uint4*>(&Ks[srow * AT_STRIDE + sseg + 8])  = k1v;
            *reinterpret_cast<uint4*>(&Vts[srow * AT_STRIDE + sseg])     = v0v;
            *reinterpret_cast<uint4*>(&Vts[srow * AT_STRIDE + sseg + 8]) = v1v;
        }
        __syncthreads();

        // S-tile: wave's 16 queries x 64 keys via MFMA (A=Q rows, B=K rows).
        floatx4 sc[4];
        #pragma unroll
        for (int jt = 0; jt < 4; ++jt) sc[jt] = (floatx4){0.f, 0.f, 0.f, 0.f};
        {
            short8 af0 = *reinterpret_cast<const short8*>(
                &Qs[(wave * 16 + c16) * AT_STRIDE + quad * 8]);
            short8 af1 = *reinterpret_cast<const short8*>(
                &Qs[(wave * 16 + c16) * AT_STRIDE + 32 + quad * 8]);
            #pragma unroll
            for (int jt = 0; jt < 4; ++jt) {
                short8 bf0 = *reinterpret_cast<const short8*>(
                    &Ks[(jt * 16 + c16) * AT_STRIDE + quad * 8]);
                short8 bf1 = *reinterpret_cast<const short8*>(
                    &Ks[(jt * 16 + c16) * AT_STRIDE + 32 + quad * 8]);
                sc[jt] = __builtin_amdgcn_mfma_f32_16x16x32_bf16(af0, bf0, sc[jt], 0, 0, 0);
                sc[jt] = __builtin_amdgcn_mfma_f32_16x16x32_bf16(af1, bf1, sc[jt], 0, 0, 0);
            }
        }

        // Band mask + online softmax. C layout: row q = quad*4+r, col j = jt*16+c16.
        #pragma unroll
        for (int r = 0; r < 4; ++r) {
            const int qg = s0 + wave * 16 + quad * 4 + r;
            float rm = -3.0e38f;
            #pragma unroll
            for (int jt = 0; jt < 4; ++jt) {
                const int jg = cb + jt * 16 + c16;
                float x = sc[jt][r];
                if (jg < qg - WIN || jg >= qg + WIN) x = -3.0e38f;
                sc[jt][r] = x;
                rm = fmaxf(rm, x);
            }
            rm = fmaxf(rm, __shfl_xor(rm, 1));
            rm = fmaxf(rm, __shfl_xor(rm, 2));
            rm = fmaxf(rm, __shfl_xor(rm, 4));
            rm = fmaxf(rm, __shfl_xor(rm, 8));
            const float mn    = fmaxf(m_[r], rm);
            const float alpha = __expf(m_[r] - mn);
            float rs = 0.f;
            #pragma unroll
            for (int jt = 0; jt < 4; ++jt) {
                const float p = __expf(sc[jt][r] - mn);
                sc[jt][r] = p;
                rs += p;
            }
            rs += __shfl_xor(rs, 1);
            rs += __shfl_xor(rs, 2);
            rs += __shfl_xor(rs, 4);
            rs += __shfl_xor(rs, 8);
            l_[r] = l_[r] * alpha + rs;
            m_[r] = mn;
            #pragma unroll
            for (int dt = 0; dt < 4; ++dt) ob[dt][r] *= alpha;
        }

        // P -> LDS (wave-private rows), bf16. Row q_local, col j.
        #pragma unroll
        for (int jt = 0; jt < 4; ++jt)
            #pragma unroll
            for (int r = 0; r < 4; ++r)
                Ps[(wave * 16 + quad * 4 + r) * AT_STRIDE + jt * 16 + c16] =
                    f2bf(sc[jt][r]);

        // O += P @ V  (A = P rows, B = Vt rows).
        {
            short8 pa0 = *reinterpret_cast<const short8*>(
                &Ps[(wave * 16 + c16) * AT_STRIDE + quad * 8]);
            short8 pa1 = *reinterpret_cast<const short8*>(
                &Ps[(wave * 16 + c16) * AT_STRIDE + 32 + quad * 8]);
            #pragma unroll
            for (int dt = 0; dt < 4; ++dt) {
                short8 bv0 = *reinterpret_cast<const short8*>(
                    &Vts[(dt * 16 + c16) * AT_STRIDE + quad * 8]);
                short8 bv1 = *reinterpret_cast<const short8*>(
                    &Vts[(dt * 16 + c16) * AT_STRIDE + 32 + quad * 8]);
                ob[dt] = __builtin_amdgcn_mfma_f32_16x16x32_bf16(pa0, bv0, ob[dt], 0, 0, 0);
                ob[dt] = __builtin_amdgcn_mfma_f32_16x16x32_bf16(pa1, bv1, ob[dt], 0, 0, 0);
            }
        }
    }

    // Epilogue: O/l -> ctx [S,B,E] f32. Row q = quad*4+r, col d = dt*16+c16.
    const int b = bh >> 4;
    const int h = bh & 15;
    #pragma unroll
    for (int r = 0; r < 4; ++r) {
        const int sg  = s0 + wave * 16 + quad * 4 + r;
        const float inv = 1.0f / l_[r];
        #pragma unroll
        for (int dt = 0; dt < 4; ++dt) {
            const int d = dt * 16 + c16;
            ctx[((size_t)(sg * BATCH + b) << 10) + (h << 6) + d] = ob[dt][r] * inv;
        }
    }
}

// ---------------------------------------------------------------------------
// Output projection via bf16 MFMA: out[m,n] = sum_k ctx[m,k]*W[n,k] + bias[n]
// ---------------------------------------------------------------------------
__global__ __launch_bounds__(256)
void out_mfma_kernel(const float* __restrict__ ctx,
                     const float* __restrict__ w,
                     const float* __restrict__ bias,
                     float* __restrict__ out)
{
    __shared__ unsigned short Asb[128 * LDS_STRIDE];
    __shared__ unsigned short Bsb[128 * LDS_STRIDE];

    const int tid   = threadIdx.x;
    const int lane  = tid & 63;
    const int wave  = tid >> 6;
    const int quad  = lane >> 4;
    const int c16   = lane & 15;
    const int wm    = (wave & 1) << 6;
    const int wn    = (wave >> 1) << 6;

    const int rowBase = blockIdx.y * 128;
    const int colBase = blockIdx.x * 128;

    const int sr = tid >> 1;
    const int cs = (tid & 1) << 4;
    const float* asrc = ctx + (size_t)(rowBase + sr) * EMB + cs;
    const float* bsrc = w   + (size_t)(colBase + sr) * EMB + cs;
    unsigned short* awr = &Asb[sr * LDS_STRIDE + cs];
    unsigned short* bwr = &Bsb[sr * LDS_STRIDE + cs];

    floatx4 acc[4][4];
    #pragma unroll
    for (int i = 0; i < 4; ++i)
        #pragma unroll
        for (int j = 0; j < 4; ++j)
            acc[i][j] = (floatx4){0.f, 0.f, 0.f, 0.f};

    for (int k0 = 0; k0 < EMB; k0 += 32) {
        __syncthreads();
        {
            float4 a0 = *reinterpret_cast<const float4*>(asrc + k0);
            float4 a1 = *reinterpret_cast<const float4*>(asrc + k0 + 4);
            float4 a2 = *reinterpret_cast<const float4*>(asrc + k0 + 8);
            float4 a3 = *reinterpret_cast<const float4*>(asrc + k0 + 12);
            float4 b0 = *reinterpret_cast<const float4*>(bsrc + k0);
            float4 b1 = *reinterpret_cast<const float4*>(bsrc + k0 + 4);
            float4 b2 = *reinterpret_cast<const float4*>(bsrc + k0 + 8);
            float4 b3 = *reinterpret_cast<const float4*>(bsrc + k0 + 12);
            uint4 pa0 = {pk2bf(a0.x,a0.y), pk2bf(a0.z,a0.w), pk2bf(a1.x,a1.y), pk2bf(a1.z,a1.w)};
            uint4 pa1 = {pk2bf(a2.x,a2.y), pk2bf(a2.z,a2.w), pk2bf(a3.x,a3.y), pk2bf(a3.z,a3.w)};
            uint4 pb0 = {pk2bf(b0.x,b0.y), pk2bf(b0.z,b0.w), pk2bf(b1.x,b1.y), pk2bf(b1.z,b1.w)};
            uint4 pb1 = {pk2bf(b2.x,b2.y), pk2bf(b2.z,b2.w), pk2bf(b3.x,b3.y), pk2bf(b3.z,b3.w)};
            *reinterpret_cast<uint4*>(awr)     = pa0;
            *reinterpret_cast<uint4*>(awr + 8) = pa1;
            *reinterpret_cast<uint4*>(bwr)     = pb0;
            *reinterpret_cast<uint4*>(bwr + 8) = pb1;
        }
        __syncthreads();

        short8 af[4], bf[4];
        #pragma unroll
        for (int mi = 0; mi < 4; ++mi)
            af[mi] = *reinterpret_cast<const short8*>(
                &Asb[(wm + mi * 16 + c16) * LDS_STRIDE + quad * 8]);
        #pragma unroll
        for (int ni = 0; ni < 4; ++ni)
            bf[ni] = *reinterpret_cast<const short8*>(
                &Bsb[(wn + ni * 16 + c16) * LDS_STRIDE + quad * 8]);

        #pragma unroll
        for (int mi = 0; mi < 4; ++mi)
            #pragma unroll
            for (int ni = 0; ni < 4; ++ni)
                acc[mi][ni] = __builtin_amdgcn_mfma_f32_16x16x32_bf16(
                    af[mi], bf[ni], acc[mi][ni], 0, 0, 0);
    }

    #pragma unroll
    for (int ni = 0; ni < 4; ++ni) {
        const int n_full = colBase + wn + ni * 16 + c16;
        const float bb = bias[n_full];
        #pragma unroll
        for (int mi = 0; mi < 4; ++mi) {
            #pragma unroll
            for (int r = 0; r < 4; ++r) {
                const int m_g = rowBase + wm + mi * 16 + quad * 4 + r;
                out[(size_t)m_g * EMB + n_full] = acc[mi][ni][r] + bb;
            }
        }
    }
}

// ---------------------------------------------------------------------------
extern "C" void kernel_launch(void* const* d_in, const int* in_sizes, int n_in,
                              void* d_out, int out_size, void* d_ws, size_t ws_size,
                              hipStream_t stream) {
    const float* query = (const float*)d_in[0];
    const float* key   = (const float*)d_in[1];
    const float* value = (const float*)d_in[2];
    const float* in_w  = (const float*)d_in[3];
    const float* in_b  = (const float*)d_in[4];
    const float* out_w = (const float*)d_in[5];
    const float* out_b = (const float*)d_in[6];

    // Workspace: q,k,vt bf16 planes (8 MB each) + ctx f32 (16 MB) = 40 MB.
    const size_t PLANE = (size_t)BATCH * NHEAD * S_LEN * HDIM;  // 4194304
    unsigned short* qo  = (unsigned short*)d_ws;
    unsigned short* ko  = qo + PLANE;
    unsigned short* vto = ko + PLANE;
    float* cw = (float*)(vto + PLANE);

    dim3 g1(EMB / 128, (S_LEN * BATCH) / 128, 3);
    qkv_mfma_kernel<<<g1, 256, 0, stream>>>(query, key, value, in_w, in_b, qo, ko, vto);

    dim3 g2(S_LEN / 64, BATCH * NHEAD);
    attn_mfma_kernel<<<g2, 256, 0, stream>>>(qo, ko, vto, cw);

    dim3 g3(EMB / 128, (S_LEN * BATCH) / 128);
    out_mfma_kernel<<<g3, 256, 0, stream>>>(cw, out_w, out_b, (float*)d_out);
}

// Round 6
// 206.913 us; speedup vs baseline: 8.8113x; 1.2499x over previous
//
#include <hip/hip_runtime.h>
#include <hip/hip_bf16.h>

// Problem constants (setup_inputs is fixed)
#define S_LEN 2048
#define BATCH 2
#define EMB   1024
#define NHEAD 16
#define HDIM  64
#define WIN   128

typedef __attribute__((ext_vector_type(8))) short short8;
typedef __attribute__((ext_vector_type(4))) float floatx4;

// Pack two f32 into two RNE-rounded bf16 (lo = a, hi = b).
__device__ __forceinline__ unsigned int pk2bf(float a, float b) {
    unsigned int ua = __builtin_bit_cast(unsigned int, a);
    unsigned int ub = __builtin_bit_cast(unsigned int, b);
    ua += 0x7fffu + ((ua >> 16) & 1u);
    ub += 0x7fffu + ((ub >> 16) & 1u);
    return (ua >> 16) | (ub & 0xffff0000u);
}
__device__ __forceinline__ unsigned short f2bf(float f) {
    unsigned int u = __builtin_bit_cast(unsigned int, f);
    u += 0x7fffu + ((u >> 16) & 1u);
    return (unsigned short)(u >> 16);
}

// Async global->LDS, 16 B per lane. LDS dest = wave-uniform base + lane*16.
__device__ __forceinline__ void gl_lds16(const unsigned short* g, unsigned short* l) {
    __builtin_amdgcn_global_load_lds(
        (const __attribute__((address_space(1))) unsigned int*)g,
        (__attribute__((address_space(3))) unsigned int*)l,
        16, 0, 0);
}

// ---------------------------------------------------------------------------
// Convert pass: f32 -> bf16 for x(q,k,v), in_proj_w, out_proj_w.
// 8 elems per thread; grid sized exactly.
// ---------------------------------------------------------------------------
#define QKV_UNITS 524288          // 4194304/8
#define WI_UNITS  393216          // 3145728/8
#define WO_UNITS  131072          // 1048576/8

__global__ __launch_bounds__(256)
void convert_kernel(const float* __restrict__ xq, const float* __restrict__ xk,
                    const float* __restrict__ xv, const float* __restrict__ wi,
                    const float* __restrict__ wo,
                    unsigned short* __restrict__ xqb, unsigned short* __restrict__ xkb,
                    unsigned short* __restrict__ xvb, unsigned short* __restrict__ wib,
                    unsigned short* __restrict__ wob)
{
    const size_t u = (size_t)blockIdx.x * 256 + threadIdx.x;
    const float* src;
    unsigned short* dst;
    size_t off;
    if (u < 3 * (size_t)QKV_UNITS) {
        const int which = (int)(u / QKV_UNITS);
        off = (u % QKV_UNITS) * 8;
        src = (which == 0) ? xq : (which == 1) ? xk : xv;
        dst = (which == 0) ? xqb : (which == 1) ? xkb : xvb;
    } else if (u < 3 * (size_t)QKV_UNITS + WI_UNITS) {
        off = (u - 3 * (size_t)QKV_UNITS) * 8;
        src = wi; dst = wib;
    } else {
        off = (u - (3 * (size_t)QKV_UNITS + WI_UNITS)) * 8;
        src = wo; dst = wob;
    }
    float4 a = *reinterpret_cast<const float4*>(src + off);
    float4 b = *reinterpret_cast<const float4*>(src + off + 4);
    uint4 p = {pk2bf(a.x, a.y), pk2bf(a.z, a.w), pk2bf(b.x, b.y), pk2bf(b.z, b.w)};
    *reinterpret_cast<uint4*>(dst + off) = p;
}

// ---------------------------------------------------------------------------
// QKV projection, m97-style bf16 MFMA GEMM: Y[m,n] = sum_k X[m,k]*W[n,k]+b[n]
// A: [4096,1024] bf16 (by z), B: [1024,1024] bf16 slice. 128x128 tile, BK=32,
// global_load_lds width=16 staging, unpadded 64B-row LDS.
// Outputs bf16: q,k as [B,H,S,D] (q scaled 0.125), v transposed [B,H,D,S].
// ---------------------------------------------------------------------------
__global__ __launch_bounds__(256)
void qkv_gemm_kernel(const unsigned short* __restrict__ xqb,
                     const unsigned short* __restrict__ xkb,
                     const unsigned short* __restrict__ xvb,
                     const unsigned short* __restrict__ wib,   // [3E, E] bf16
                     const float* __restrict__ bias,           // [3E] f32
                     unsigned short* __restrict__ qo,
                     unsigned short* __restrict__ ko,
                     unsigned short* __restrict__ vto)
{
    __shared__ unsigned short As[128 * 32];
    __shared__ unsigned short Bs[128 * 32];

    const int which = blockIdx.z;
    const unsigned short* A = (which == 0) ? xqb : (which == 1) ? xkb : xvb;
    const unsigned short* W = wib + (size_t)which * EMB * EMB;
    const float* bv = bias + which * EMB;
    const float scale = (which == 0) ? 0.125f : 1.0f;

    const int tid  = threadIdx.x;
    const int lane = tid & 63;
    const int wave = tid >> 6;
    const int quad = lane >> 4;
    const int c16  = lane & 15;
    const int wm   = (wave & 1) << 6;
    const int wn   = (wave >> 1) << 6;

    const int rowBase = blockIdx.y * 128;
    const int colBase = blockIdx.x * 128;

    // Per-wave staging: chunk c = wave*2+t covers rows [c*16, c*16+16).
    const int lrow = lane >> 2;            // 0..15 within chunk
    const int lseg = (lane & 3) << 3;      // 0,8,16,24 (ushorts)

    floatx4 acc[4][4];
    #pragma unroll
    for (int i = 0; i < 4; ++i)
        #pragma unroll
        for (int j = 0; j < 4; ++j)
            acc[i][j] = (floatx4){0.f, 0.f, 0.f, 0.f};

    for (int k0 = 0; k0 < EMB; k0 += 32) {
        __syncthreads();   // prior iter's ds_reads done before LDS overwrite
        #pragma unroll
        for (int t = 0; t < 2; ++t) {
            const int c = wave * 2 + t;
            const int row = c * 16 + lrow;
            gl_lds16(A + (size_t)(rowBase + row) * EMB + k0 + lseg, &As[c * 512]);
            gl_lds16(W + (size_t)(colBase + row) * EMB + k0 + lseg, &Bs[c * 512]);
        }
        __syncthreads();   // vmcnt drained by compiler before barrier

        short8 af[4], bf[4];
        #pragma unroll
        for (int mi = 0; mi < 4; ++mi)
            af[mi] = *reinterpret_cast<const short8*>(
                &As[(wm + mi * 16 + c16) * 32 + quad * 8]);
        #pragma unroll
        for (int ni = 0; ni < 4; ++ni)
            bf[ni] = *reinterpret_cast<const short8*>(
                &Bs[(wn + ni * 16 + c16) * 32 + quad * 8]);

        #pragma unroll
        for (int mi = 0; mi < 4; ++mi)
            #pragma unroll
            for (int ni = 0; ni < 4; ++ni)
                acc[mi][ni] = __builtin_amdgcn_mfma_f32_16x16x32_bf16(
                    af[mi], bf[ni], acc[mi][ni], 0, 0, 0);
    }

    // Epilogue -> bf16. D[m = quad*4+r][n = c16] per 16x16 tile.
    #pragma unroll
    for (int ni = 0; ni < 4; ++ni) {
        const int n_full = colBase + wn + ni * 16 + c16;   // 0..1023
        const float bb = bv[n_full];
        const int h = n_full >> 6;
        const int d = n_full & 63;
        #pragma unroll
        for (int mi = 0; mi < 4; ++mi) {
            #pragma unroll
            for (int r = 0; r < 4; ++r) {
                const int m_g = rowBase + wm + mi * 16 + quad * 4 + r;
                const int s   = m_g >> 1;      // m = s*B + b
                const int b   = m_g & 1;
                const int bh  = b * NHEAD + h;
                const unsigned short val = f2bf((acc[mi][ni][r] + bb) * scale);
                if (which == 2)
                    vto[((size_t)bh * HDIM + d) * S_LEN + s] = val;
                else if (which == 0)
                    qo[((size_t)bh * S_LEN + s) * HDIM + d] = val;
                else
                    ko[((size_t)bh * S_LEN + s) * HDIM + d] = val;
            }
        }
    }
}

// ---------------------------------------------------------------------------
// MFMA flash attention over the band (as round 5), ctx out now bf16.
// ---------------------------------------------------------------------------
#define AT_STRIDE 72   // ushorts per LDS row (144B; breaks bank alignment)

__global__ __launch_bounds__(256)
void attn_mfma_kernel(const unsigned short* __restrict__ q,
                      const unsigned short* __restrict__ k,
                      const unsigned short* __restrict__ vt,
                      unsigned short* __restrict__ ctx)
{
    __shared__ unsigned short Qs[64 * AT_STRIDE];
    __shared__ unsigned short Ks[64 * AT_STRIDE];
    __shared__ unsigned short Vts[64 * AT_STRIDE];
    __shared__ unsigned short Ps[64 * AT_STRIDE];

    const int bh  = blockIdx.y;
    const int s0  = blockIdx.x * 64;
    const int tid = threadIdx.x;
    const int lane = tid & 63;
    const int wave = tid >> 6;
    const int quad = lane >> 4;
    const int c16  = lane & 15;

    const size_t base_qk = ((size_t)bh * S_LEN) * HDIM;
    const size_t base_vt = ((size_t)bh * HDIM) * S_LEN;

    const int srow = tid >> 2;
    const int sseg = (tid & 3) << 4;
    {
        const unsigned short* src = q + base_qk + (size_t)(s0 + srow) * HDIM + sseg;
        uint4 v0 = *reinterpret_cast<const uint4*>(src);
        uint4 v1 = *reinterpret_cast<const uint4*>(src + 8);
        *reinterpret_cast<uint4*>(&Qs[srow * AT_STRIDE + sseg])     = v0;
        *reinterpret_cast<uint4*>(&Qs[srow * AT_STRIDE + sseg + 8]) = v1;
    }

    float m_[4], l_[4];
    floatx4 ob[4];
    #pragma unroll
    for (int r = 0; r < 4; ++r) { m_[r] = -1.0e30f; l_[r] = 0.f; }
    #pragma unroll
    for (int dt = 0; dt < 4; ++dt) ob[dt] = (floatx4){0.f, 0.f, 0.f, 0.f};

    int c0 = s0 - 128; if (c0 < 0) c0 = 0;
    int c1 = s0 + 192; if (c1 > S_LEN) c1 = S_LEN;

    for (int cb = c0; cb < c1; cb += 64) {
        __syncthreads();
        {
            const unsigned short* ksrc = k + base_qk + (size_t)(cb + srow) * HDIM + sseg;
            const unsigned short* vsrc = vt + base_vt + (size_t)srow * S_LEN + cb + sseg;
            uint4 k0v = *reinterpret_cast<const uint4*>(ksrc);
            uint4 k1v = *reinterpret_cast<const uint4*>(ksrc + 8);
            uint4 v0v = *reinterpret_cast<const uint4*>(vsrc);
            uint4 v1v = *reinterpret_cast<const uint4*>(vsrc + 8);
            *reinterpret_cast<uint4*>(&Ks[srow * AT_STRIDE + sseg])      = k0v;
            *reinterpret_cast<uint4*>(&Ks[srow * AT_STRIDE + sseg + 8])  = k1v;
            *reinterpret_cast<uint4*>(&Vts[srow * AT_STRIDE + sseg])     = v0v;
            *reinterpret_cast<uint4*>(&Vts[srow * AT_STRIDE + sseg + 8]) = v1v;
        }
        __syncthreads();

        floatx4 sc[4];
        #pragma unroll
        for (int jt = 0; jt < 4; ++jt) sc[jt] = (floatx4){0.f, 0.f, 0.f, 0.f};
        {
            short8 af0 = *reinterpret_cast<const short8*>(
                &Qs[(wave * 16 + c16) * AT_STRIDE + quad * 8]);
            short8 af1 = *reinterpret_cast<const short8*>(
                &Qs[(wave * 16 + c16) * AT_STRIDE + 32 + quad * 8]);
            #pragma unroll
            for (int jt = 0; jt < 4; ++jt) {
                short8 bf0 = *reinterpret_cast<const short8*>(
                    &Ks[(jt * 16 + c16) * AT_STRIDE + quad * 8]);
                short8 bf1 = *reinterpret_cast<const short8*>(
                    &Ks[(jt * 16 + c16) * AT_STRIDE + 32 + quad * 8]);
                sc[jt] = __builtin_amdgcn_mfma_f32_16x16x32_bf16(af0, bf0, sc[jt], 0, 0, 0);
                sc[jt] = __builtin_amdgcn_mfma_f32_16x16x32_bf16(af1, bf1, sc[jt], 0, 0, 0);
            }
        }

        #pragma unroll
        for (int r = 0; r < 4; ++r) {
            const int qg = s0 + wave * 16 + quad * 4 + r;
            float rm = -3.0e38f;
            #pragma unroll
            for (int jt = 0; jt < 4; ++jt) {
                const int jg = cb + jt * 16 + c16;
                float x = sc[jt][r];
                if (jg < qg - WIN || jg >= qg + WIN) x = -3.0e38f;
                sc[jt][r] = x;
                rm = fmaxf(rm, x);
            }
            rm = fmaxf(rm, __shfl_xor(rm, 1));
            rm = fmaxf(rm, __shfl_xor(rm, 2));
            rm = fmaxf(rm, __shfl_xor(rm, 4));
            rm = fmaxf(rm, __shfl_xor(rm, 8));
            const float mn    = fmaxf(m_[r], rm);
            const float alpha = __expf(m_[r] - mn);
            float rs = 0.f;
            #pragma unroll
            for (int jt = 0; jt < 4; ++jt) {
                const float p = __expf(sc[jt][r] - mn);
                sc[jt][r] = p;
                rs += p;
            }
            rs += __shfl_xor(rs, 1);
            rs += __shfl_xor(rs, 2);
            rs += __shfl_xor(rs, 4);
            rs += __shfl_xor(rs, 8);
            l_[r] = l_[r] * alpha + rs;
            m_[r] = mn;
            #pragma unroll
            for (int dt = 0; dt < 4; ++dt) ob[dt][r] *= alpha;
        }

        #pragma unroll
        for (int jt = 0; jt < 4; ++jt)
            #pragma unroll
            for (int r = 0; r < 4; ++r)
                Ps[(wave * 16 + quad * 4 + r) * AT_STRIDE + jt * 16 + c16] =
                    f2bf(sc[jt][r]);

        {
            short8 pa0 = *reinterpret_cast<const short8*>(
                &Ps[(wave * 16 + c16) * AT_STRIDE + quad * 8]);
            short8 pa1 = *reinterpret_cast<const short8*>(
                &Ps[(wave * 16 + c16) * AT_STRIDE + 32 + quad * 8]);
            #pragma unroll
            for (int dt = 0; dt < 4; ++dt) {
                short8 bv0 = *reinterpret_cast<const short8*>(
                    &Vts[(dt * 16 + c16) * AT_STRIDE + quad * 8]);
                short8 bv1 = *reinterpret_cast<const short8*>(
                    &Vts[(dt * 16 + c16) * AT_STRIDE + 32 + quad * 8]);
                ob[dt] = __builtin_amdgcn_mfma_f32_16x16x32_bf16(pa0, bv0, ob[dt], 0, 0, 0);
                ob[dt] = __builtin_amdgcn_mfma_f32_16x16x32_bf16(pa1, bv1, ob[dt], 0, 0, 0);
            }
        }
    }

    // Epilogue: O/l -> ctx [S,B,E] bf16.
    const int b = bh >> 4;
    const int h = bh & 15;
    #pragma unroll
    for (int r = 0; r < 4; ++r) {
        const int sg  = s0 + wave * 16 + quad * 4 + r;
        const float inv = 1.0f / l_[r];
        #pragma unroll
        for (int dt = 0; dt < 4; ++dt) {
            const int d = dt * 16 + c16;
            ctx[((size_t)(sg * BATCH + b) << 10) + (h << 6) + d] = f2bf(ob[dt][r] * inv);
        }
    }
}

// ---------------------------------------------------------------------------
// Output projection, m97-style: out[m,n] = sum_k ctx[m,k]*W[n,k] + bias[n]
// ctx: [4096,1024] bf16, W: [1024,1024] bf16, out: [S,B,E] f32.
// ---------------------------------------------------------------------------
__global__ __launch_bounds__(256)
void out_gemm_kernel(const unsigned short* __restrict__ ctxb,
                     const unsigned short* __restrict__ wob,
                     const float* __restrict__ bias,
                     float* __restrict__ out)
{
    __shared__ unsigned short As[128 * 32];
    __shared__ unsigned short Bs[128 * 32];

    const int tid  = threadIdx.x;
    const int lane = tid & 63;
    const int wave = tid >> 6;
    const int quad = lane >> 4;
    const int c16  = lane & 15;
    const int wm   = (wave & 1) << 6;
    const int wn   = (wave >> 1) << 6;

    const int rowBase = blockIdx.y * 128;
    const int colBase = blockIdx.x * 128;

    const int lrow = lane >> 2;
    const int lseg = (lane & 3) << 3;

    floatx4 acc[4][4];
    #pragma unroll
    for (int i = 0; i < 4; ++i)
        #pragma unroll
        for (int j = 0; j < 4; ++j)
            acc[i][j] = (floatx4){0.f, 0.f, 0.f, 0.f};

    for (int k0 = 0; k0 < EMB; k0 += 32) {
        __syncthreads();
        #pragma unroll
        for (int t = 0; t < 2; ++t) {
            const int c = wave * 2 + t;
            const int row = c * 16 + lrow;
            gl_lds16(ctxb + (size_t)(rowBase + row) * EMB + k0 + lseg, &As[c * 512]);
            gl_lds16(wob  + (size_t)(colBase + row) * EMB + k0 + lseg, &Bs[c * 512]);
        }
        __syncthreads();

        short8 af[4], bf[4];
        #pragma unroll
        for (int mi = 0; mi < 4; ++mi)
            af[mi] = *reinterpret_cast<const short8*>(
                &As[(wm + mi * 16 + c16) * 32 + quad * 8]);
        #pragma unroll
        for (int ni = 0; ni < 4; ++ni)
            bf[ni] = *reinterpret_cast<const short8*>(
                &Bs[(wn + ni * 16 + c16) * 32 + quad * 8]);

        #pragma unroll
        for (int mi = 0; mi < 4; ++mi)
            #pragma unroll
            for (int ni = 0; ni < 4; ++ni)
                acc[mi][ni] = __builtin_amdgcn_mfma_f32_16x16x32_bf16(
                    af[mi], bf[ni], acc[mi][ni], 0, 0, 0);
    }

    #pragma unroll
    for (int ni = 0; ni < 4; ++ni) {
        const int n_full = colBase + wn + ni * 16 + c16;
        const float bb = bias[n_full];
        #pragma unroll
        for (int mi = 0; mi < 4; ++mi) {
            #pragma unroll
            for (int r = 0; r < 4; ++r) {
                const int m_g = rowBase + wm + mi * 16 + quad * 4 + r;
                out[(size_t)m_g * EMB + n_full] = acc[mi][ni][r] + bb;
            }
        }
    }
}

// ---------------------------------------------------------------------------
extern "C" void kernel_launch(void* const* d_in, const int* in_sizes, int n_in,
                              void* d_out, int out_size, void* d_ws, size_t ws_size,
                              hipStream_t stream) {
    const float* query = (const float*)d_in[0];
    const float* key   = (const float*)d_in[1];
    const float* value = (const float*)d_in[2];
    const float* in_w  = (const float*)d_in[3];
    const float* in_b  = (const float*)d_in[4];
    const float* out_w = (const float*)d_in[5];
    const float* out_b = (const float*)d_in[6];

    // Workspace (ushorts): xq,xk,xv bf16 (4M each) + wi (3M) + wo (1M)
    //                    + q,k,vt (4M each) + ctx (4M)  = 33.5M ushort = 64 MB.
    const size_t PLANE = (size_t)BATCH * NHEAD * S_LEN * HDIM;  // 4194304
    unsigned short* xqb = (unsigned short*)d_ws;
    unsigned short* xkb = xqb + PLANE;
    unsigned short* xvb = xkb + PLANE;
    unsigned short* wib = xvb + PLANE;                 // 3*EMB*EMB
    unsigned short* wob = wib + (size_t)3 * EMB * EMB; // EMB*EMB
    unsigned short* qo  = wob + (size_t)EMB * EMB;
    unsigned short* ko  = qo + PLANE;
    unsigned short* vto = ko + PLANE;
    unsigned short* cw  = vto + PLANE;

    convert_kernel<<<8192, 256, 0, stream>>>(query, key, value, in_w, out_w,
                                             xqb, xkb, xvb, wib, wob);

    dim3 g1(EMB / 128, (S_LEN * BATCH) / 128, 3);
    qkv_gemm_kernel<<<g1, 256, 0, stream>>>(xqb, xkb, xvb, wib, in_b, qo, ko, vto);

    dim3 g2(S_LEN / 64, BATCH * NHEAD);
    attn_mfma_kernel<<<g2, 256, 0, stream>>>(qo, ko, vto, cw);

    dim3 g3(EMB / 128, (S_LEN * BATCH) / 128);
    out_gemm_kernel<<<g3, 256, 0, stream>>>(cw, wob, out_b, (float*)d_out);
}

// Round 7
// 199.837 us; speedup vs baseline: 9.1233x; 1.0354x over previous
//
#include <hip/hip_runtime.h>
#include <hip/hip_bf16.h>

// Problem constants (setup_inputs is fixed)
#define S_LEN 2048
#define BATCH 2
#define EMB   1024
#define NHEAD 16
#define HDIM  64
#define WIN   128

typedef __attribute__((ext_vector_type(8))) short short8;
typedef __attribute__((ext_vector_type(4))) float floatx4;

// Pack two f32 into two RNE-rounded bf16 (lo = a, hi = b).
__device__ __forceinline__ unsigned int pk2bf(float a, float b) {
    unsigned int ua = __builtin_bit_cast(unsigned int, a);
    unsigned int ub = __builtin_bit_cast(unsigned int, b);
    ua += 0x7fffu + ((ua >> 16) & 1u);
    ub += 0x7fffu + ((ub >> 16) & 1u);
    return (ua >> 16) | (ub & 0xffff0000u);
}
__device__ __forceinline__ unsigned short f2bf(float f) {
    unsigned int u = __builtin_bit_cast(unsigned int, f);
    u += 0x7fffu + ((u >> 16) & 1u);
    return (unsigned short)(u >> 16);
}

// Async global->LDS, 16 B per lane. LDS dest = wave-uniform base + lane*16.
__device__ __forceinline__ void gl_lds16(const unsigned short* g, unsigned short* l) {
    __builtin_amdgcn_global_load_lds(
        (const __attribute__((address_space(1))) unsigned int*)g,
        (__attribute__((address_space(3))) unsigned int*)l,
        16, 0, 0);
}

// ---------------------------------------------------------------------------
// Convert pass: f32 -> bf16 for x(q,k,v), in_proj_w, out_proj_w.
// ---------------------------------------------------------------------------
#define QKV_UNITS 524288          // 4194304/8
#define WI_UNITS  393216          // 3145728/8
#define WO_UNITS  131072          // 1048576/8

__global__ __launch_bounds__(256)
void convert_kernel(const float* __restrict__ xq, const float* __restrict__ xk,
                    const float* __restrict__ xv, const float* __restrict__ wi,
                    const float* __restrict__ wo,
                    unsigned short* __restrict__ xqb, unsigned short* __restrict__ xkb,
                    unsigned short* __restrict__ xvb, unsigned short* __restrict__ wib,
                    unsigned short* __restrict__ wob)
{
    const size_t u = (size_t)blockIdx.x * 256 + threadIdx.x;
    const float* src;
    unsigned short* dst;
    size_t off;
    if (u < 3 * (size_t)QKV_UNITS) {
        const int which = (int)(u / QKV_UNITS);
        off = (u % QKV_UNITS) * 8;
        src = (which == 0) ? xq : (which == 1) ? xk : xv;
        dst = (which == 0) ? xqb : (which == 1) ? xkb : xvb;
    } else if (u < 3 * (size_t)QKV_UNITS + WI_UNITS) {
        off = (u - 3 * (size_t)QKV_UNITS) * 8;
        src = wi; dst = wib;
    } else {
        off = (u - (3 * (size_t)QKV_UNITS + WI_UNITS)) * 8;
        src = wo; dst = wob;
    }
    float4 a = *reinterpret_cast<const float4*>(src + off);
    float4 b = *reinterpret_cast<const float4*>(src + off + 4);
    uint4 p = {pk2bf(a.x, a.y), pk2bf(a.z, a.w), pk2bf(b.x, b.y), pk2bf(b.z, b.w)};
    *reinterpret_cast<uint4*>(dst + off) = p;
}

// ---------------------------------------------------------------------------
// QKV projection, m97-style bf16 MFMA GEMM. 1D grid, XCD-swizzled:
// bid = z*256 + x*32 + y  ->  XCD = bid%8 = y%8, so all 8 col-tiles (x) of a
// row-panel (y) land on the same XCD: A-rows fetched once per XCD-L2.
// Outputs bf16: q,k as [B,H,S,D] (q scaled 0.125), v transposed [B,H,D,S].
// ---------------------------------------------------------------------------
__global__ __launch_bounds__(256)
void qkv_gemm_kernel(const unsigned short* __restrict__ xqb,
                     const unsigned short* __restrict__ xkb,
                     const unsigned short* __restrict__ xvb,
                     const unsigned short* __restrict__ wib,   // [3E, E] bf16
                     const float* __restrict__ bias,           // [3E] f32
                     unsigned short* __restrict__ qo,
                     unsigned short* __restrict__ ko,
                     unsigned short* __restrict__ vto)
{
    __shared__ unsigned short As[128 * 32];
    __shared__ unsigned short Bs[128 * 32];

    const int bid  = blockIdx.x;
    const int which = bid >> 8;            // z
    const int bx   = (bid >> 5) & 7;       // col-tile
    const int by   = bid & 31;             // row-panel (XCD key)

    const unsigned short* A = (which == 0) ? xqb : (which == 1) ? xkb : xvb;
    const unsigned short* W = wib + (size_t)which * EMB * EMB;
    const float* bv = bias + which * EMB;
    const float scale = (which == 0) ? 0.125f : 1.0f;

    const int tid  = threadIdx.x;
    const int lane = tid & 63;
    const int wave = tid >> 6;
    const int quad = lane >> 4;
    const int c16  = lane & 15;
    const int wm   = (wave & 1) << 6;
    const int wn   = (wave >> 1) << 6;

    const int rowBase = by * 128;
    const int colBase = bx * 128;

    const int lrow = lane >> 2;            // 0..15 within chunk
    const int lseg = (lane & 3) << 3;      // 0,8,16,24 (ushorts)

    floatx4 acc[4][4];
    #pragma unroll
    for (int i = 0; i < 4; ++i)
        #pragma unroll
        for (int j = 0; j < 4; ++j)
            acc[i][j] = (floatx4){0.f, 0.f, 0.f, 0.f};

    for (int k0 = 0; k0 < EMB; k0 += 32) {
        __syncthreads();
        #pragma unroll
        for (int t = 0; t < 2; ++t) {
            const int c = wave * 2 + t;
            const int row = c * 16 + lrow;
            gl_lds16(A + (size_t)(rowBase + row) * EMB + k0 + lseg, &As[c * 512]);
            gl_lds16(W + (size_t)(colBase + row) * EMB + k0 + lseg, &Bs[c * 512]);
        }
        __syncthreads();

        short8 af[4], bf[4];
        #pragma unroll
        for (int mi = 0; mi < 4; ++mi)
            af[mi] = *reinterpret_cast<const short8*>(
                &As[(wm + mi * 16 + c16) * 32 + quad * 8]);
        #pragma unroll
        for (int ni = 0; ni < 4; ++ni)
            bf[ni] = *reinterpret_cast<const short8*>(
                &Bs[(wn + ni * 16 + c16) * 32 + quad * 8]);

        #pragma unroll
        for (int mi = 0; mi < 4; ++mi)
            #pragma unroll
            for (int ni = 0; ni < 4; ++ni)
                acc[mi][ni] = __builtin_amdgcn_mfma_f32_16x16x32_bf16(
                    af[mi], bf[ni], acc[mi][ni], 0, 0, 0);
    }

    // Epilogue -> bf16. D[m = quad*4+r][n = c16] per 16x16 tile.
    #pragma unroll
    for (int ni = 0; ni < 4; ++ni) {
        const int n_full = colBase + wn + ni * 16 + c16;   // 0..1023
        const float bb = bv[n_full];
        const int h = n_full >> 6;
        const int d = n_full & 63;
        #pragma unroll
        for (int mi = 0; mi < 4; ++mi) {
            #pragma unroll
            for (int r = 0; r < 4; ++r) {
                const int m_g = rowBase + wm + mi * 16 + quad * 4 + r;
                const int s   = m_g >> 1;      // m = s*B + b
                const int b   = m_g & 1;
                const int bh  = b * NHEAD + h;
                const unsigned short val = f2bf((acc[mi][ni][r] + bb) * scale);
                if (which == 2)
                    vto[((size_t)bh * HDIM + d) * S_LEN + s] = val;
                else if (which == 0)
                    qo[((size_t)bh * S_LEN + s) * HDIM + d] = val;
                else
                    ko[((size_t)bh * S_LEN + s) * HDIM + d] = val;
            }
        }
    }
}

// ---------------------------------------------------------------------------
// MFMA flash attention over the band. 1D grid, XCD-swizzled:
// bid = sx*32 + bh -> XCD = bh%8: all s-tiles of a head (and their band
// overlap) stay on one XCD. ctx out bf16.
// ---------------------------------------------------------------------------
#define AT_STRIDE 72   // ushorts per LDS row (144B)

__global__ __launch_bounds__(256)
void attn_mfma_kernel(const unsigned short* __restrict__ q,
                      const unsigned short* __restrict__ k,
                      const unsigned short* __restrict__ vt,
                      unsigned short* __restrict__ ctx)
{
    __shared__ unsigned short Qs[64 * AT_STRIDE];
    __shared__ unsigned short Ks[64 * AT_STRIDE];
    __shared__ unsigned short Vts[64 * AT_STRIDE];
    __shared__ unsigned short Ps[64 * AT_STRIDE];

    const int bid = blockIdx.x;
    const int bh  = bid & 31;
    const int s0  = (bid >> 5) * 64;
    const int tid = threadIdx.x;
    const int lane = tid & 63;
    const int wave = tid >> 6;
    const int quad = lane >> 4;
    const int c16  = lane & 15;

    const size_t base_qk = ((size_t)bh * S_LEN) * HDIM;
    const size_t base_vt = ((size_t)bh * HDIM) * S_LEN;

    const int srow = tid >> 2;
    const int sseg = (tid & 3) << 4;
    {
        const unsigned short* src = q + base_qk + (size_t)(s0 + srow) * HDIM + sseg;
        uint4 v0 = *reinterpret_cast<const uint4*>(src);
        uint4 v1 = *reinterpret_cast<const uint4*>(src + 8);
        *reinterpret_cast<uint4*>(&Qs[srow * AT_STRIDE + sseg])     = v0;
        *reinterpret_cast<uint4*>(&Qs[srow * AT_STRIDE + sseg + 8]) = v1;
    }

    float m_[4], l_[4];
    floatx4 ob[4];
    #pragma unroll
    for (int r = 0; r < 4; ++r) { m_[r] = -1.0e30f; l_[r] = 0.f; }
    #pragma unroll
    for (int dt = 0; dt < 4; ++dt) ob[dt] = (floatx4){0.f, 0.f, 0.f, 0.f};

    int c0 = s0 - 128; if (c0 < 0) c0 = 0;
    int c1 = s0 + 192; if (c1 > S_LEN) c1 = S_LEN;

    for (int cb = c0; cb < c1; cb += 64) {
        __syncthreads();
        {
            const unsigned short* ksrc = k + base_qk + (size_t)(cb + srow) * HDIM + sseg;
            const unsigned short* vsrc = vt + base_vt + (size_t)srow * S_LEN + cb + sseg;
            uint4 k0v = *reinterpret_cast<const uint4*>(ksrc);
            uint4 k1v = *reinterpret_cast<const uint4*>(ksrc + 8);
            uint4 v0v = *reinterpret_cast<const uint4*>(vsrc);
            uint4 v1v = *reinterpret_cast<const uint4*>(vsrc + 8);
            *reinterpret_cast<uint4*>(&Ks[srow * AT_STRIDE + sseg])      = k0v;
            *reinterpret_cast<uint4*>(&Ks[srow * AT_STRIDE + sseg + 8])  = k1v;
            *reinterpret_cast<uint4*>(&Vts[srow * AT_STRIDE + sseg])     = v0v;
            *reinterpret_cast<uint4*>(&Vts[srow * AT_STRIDE + sseg + 8]) = v1v;
        }
        __syncthreads();

        floatx4 sc[4];
        #pragma unroll
        for (int jt = 0; jt < 4; ++jt) sc[jt] = (floatx4){0.f, 0.f, 0.f, 0.f};
        {
            short8 af0 = *reinterpret_cast<const short8*>(
                &Qs[(wave * 16 + c16) * AT_STRIDE + quad * 8]);
            short8 af1 = *reinterpret_cast<const short8*>(
                &Qs[(wave * 16 + c16) * AT_STRIDE + 32 + quad * 8]);
            #pragma unroll
            for (int jt = 0; jt < 4; ++jt) {
                short8 bf0 = *reinterpret_cast<const short8*>(
                    &Ks[(jt * 16 + c16) * AT_STRIDE + quad * 8]);
                short8 bf1 = *reinterpret_cast<const short8*>(
                    &Ks[(jt * 16 + c16) * AT_STRIDE + 32 + quad * 8]);
                sc[jt] = __builtin_amdgcn_mfma_f32_16x16x32_bf16(af0, bf0, sc[jt], 0, 0, 0);
                sc[jt] = __builtin_amdgcn_mfma_f32_16x16x32_bf16(af1, bf1, sc[jt], 0, 0, 0);
            }
        }

        #pragma unroll
        for (int r = 0; r < 4; ++r) {
            const int qg = s0 + wave * 16 + quad * 4 + r;
            float rm = -3.0e38f;
            #pragma unroll
            for (int jt = 0; jt < 4; ++jt) {
                const int jg = cb + jt * 16 + c16;
                float x = sc[jt][r];
                if (jg < qg - WIN || jg >= qg + WIN) x = -3.0e38f;
                sc[jt][r] = x;
                rm = fmaxf(rm, x);
            }
            rm = fmaxf(rm, __shfl_xor(rm, 1));
            rm = fmaxf(rm, __shfl_xor(rm, 2));
            rm = fmaxf(rm, __shfl_xor(rm, 4));
            rm = fmaxf(rm, __shfl_xor(rm, 8));
            const float mn    = fmaxf(m_[r], rm);
            const float alpha = __expf(m_[r] - mn);
            float rs = 0.f;
            #pragma unroll
            for (int jt = 0; jt < 4; ++jt) {
                const float p = __expf(sc[jt][r] - mn);
                sc[jt][r] = p;
                rs += p;
            }
            rs += __shfl_xor(rs, 1);
            rs += __shfl_xor(rs, 2);
            rs += __shfl_xor(rs, 4);
            rs += __shfl_xor(rs, 8);
            l_[r] = l_[r] * alpha + rs;
            m_[r] = mn;
            #pragma unroll
            for (int dt = 0; dt < 4; ++dt) ob[dt][r] *= alpha;
        }

        #pragma unroll
        for (int jt = 0; jt < 4; ++jt)
            #pragma unroll
            for (int r = 0; r < 4; ++r)
                Ps[(wave * 16 + quad * 4 + r) * AT_STRIDE + jt * 16 + c16] =
                    f2bf(sc[jt][r]);

        {
            short8 pa0 = *reinterpret_cast<const short8*>(
                &Ps[(wave * 16 + c16) * AT_STRIDE + quad * 8]);
            short8 pa1 = *reinterpret_cast<const short8*>(
                &Ps[(wave * 16 + c16) * AT_STRIDE + 32 + quad * 8]);
            #pragma unroll
            for (int dt = 0; dt < 4; ++dt) {
                short8 bv0 = *reinterpret_cast<const short8*>(
                    &Vts[(dt * 16 + c16) * AT_STRIDE + quad * 8]);
                short8 bv1 = *reinterpret_cast<const short8*>(
                    &Vts[(dt * 16 + c16) * AT_STRIDE + 32 + quad * 8]);
                ob[dt] = __builtin_amdgcn_mfma_f32_16x16x32_bf16(pa0, bv0, ob[dt], 0, 0, 0);
                ob[dt] = __builtin_amdgcn_mfma_f32_16x16x32_bf16(pa1, bv1, ob[dt], 0, 0, 0);
            }
        }
    }

    // Epilogue: O/l -> ctx [S,B,E] bf16.
    const int b = bh >> 4;
    const int h = bh & 15;
    #pragma unroll
    for (int r = 0; r < 4; ++r) {
        const int sg  = s0 + wave * 16 + quad * 4 + r;
        const float inv = 1.0f / l_[r];
        #pragma unroll
        for (int dt = 0; dt < 4; ++dt) {
            const int d = dt * 16 + c16;
            ctx[((size_t)(sg * BATCH + b) << 10) + (h << 6) + d] = f2bf(ob[dt][r] * inv);
        }
    }
}

// ---------------------------------------------------------------------------
// Output projection, m97-style, XCD-swizzled 1D grid (bid = x*32 + y).
// ctx: [4096,1024] bf16, W: [1024,1024] bf16, out: [S,B,E] f32.
// ---------------------------------------------------------------------------
__global__ __launch_bounds__(256)
void out_gemm_kernel(const unsigned short* __restrict__ ctxb,
                     const unsigned short* __restrict__ wob,
                     const float* __restrict__ bias,
                     float* __restrict__ out)
{
    __shared__ unsigned short As[128 * 32];
    __shared__ unsigned short Bs[128 * 32];

    const int bid = blockIdx.x;
    const int bx  = bid >> 5;
    const int by  = bid & 31;

    const int tid  = threadIdx.x;
    const int lane = tid & 63;
    const int wave = tid >> 6;
    const int quad = lane >> 4;
    const int c16  = lane & 15;
    const int wm   = (wave & 1) << 6;
    const int wn   = (wave >> 1) << 6;

    const int rowBase = by * 128;
    const int colBase = bx * 128;

    const int lrow = lane >> 2;
    const int lseg = (lane & 3) << 3;

    floatx4 acc[4][4];
    #pragma unroll
    for (int i = 0; i < 4; ++i)
        #pragma unroll
        for (int j = 0; j < 4; ++j)
            acc[i][j] = (floatx4){0.f, 0.f, 0.f, 0.f};

    for (int k0 = 0; k0 < EMB; k0 += 32) {
        __syncthreads();
        #pragma unroll
        for (int t = 0; t < 2; ++t) {
            const int c = wave * 2 + t;
            const int row = c * 16 + lrow;
            gl_lds16(ctxb + (size_t)(rowBase + row) * EMB + k0 + lseg, &As[c * 512]);
            gl_lds16(wob  + (size_t)(colBase + row) * EMB + k0 + lseg, &Bs[c * 512]);
        }
        __syncthreads();

        short8 af[4], bf[4];
        #pragma unroll
        for (int mi = 0; mi < 4; ++mi)
            af[mi] = *reinterpret_cast<const short8*>(
                &As[(wm + mi * 16 + c16) * 32 + quad * 8]);
        #pragma unroll
        for (int ni = 0; ni < 4; ++ni)
            bf[ni] = *reinterpret_cast<const short8*>(
                &Bs[(wn + ni * 16 + c16) * 32 + quad * 8]);

        #pragma unroll
        for (int mi = 0; mi < 4; ++mi)
            #pragma unroll
            for (int ni = 0; ni < 4; ++ni)
                acc[mi][ni] = __builtin_amdgcn_mfma_f32_16x16x32_bf16(
                    af[mi], bf[ni], acc[mi][ni], 0, 0, 0);
    }

    #pragma unroll
    for (int ni = 0; ni < 4; ++ni) {
        const int n_full = colBase + wn + ni * 16 + c16;
        const float bb = bias[n_full];
        #pragma unroll
        for (int mi = 0; mi < 4; ++mi) {
            #pragma unroll
            for (int r = 0; r < 4; ++r) {
                const int m_g = rowBase + wm + mi * 16 + quad * 4 + r;
                out[(size_t)m_g * EMB + n_full] = acc[mi][ni][r] + bb;
            }
        }
    }
}

// ---------------------------------------------------------------------------
extern "C" void kernel_launch(void* const* d_in, const int* in_sizes, int n_in,
                              void* d_out, int out_size, void* d_ws, size_t ws_size,
                              hipStream_t stream) {
    const float* query = (const float*)d_in[0];
    const float* key   = (const float*)d_in[1];
    const float* value = (const float*)d_in[2];
    const float* in_w  = (const float*)d_in[3];
    const float* in_b  = (const float*)d_in[4];
    const float* out_w = (const float*)d_in[5];
    const float* out_b = (const float*)d_in[6];

    const size_t PLANE = (size_t)BATCH * NHEAD * S_LEN * HDIM;  // 4194304
    unsigned short* xqb = (unsigned short*)d_ws;
    unsigned short* xkb = xqb + PLANE;
    unsigned short* xvb = xkb + PLANE;
    unsigned short* wib = xvb + PLANE;                 // 3*EMB*EMB
    unsigned short* wob = wib + (size_t)3 * EMB * EMB; // EMB*EMB
    unsigned short* qo  = wob + (size_t)EMB * EMB;
    unsigned short* ko  = qo + PLANE;
    unsigned short* vto = ko + PLANE;
    unsigned short* cw  = vto + PLANE;

    convert_kernel<<<8192, 256, 0, stream>>>(query, key, value, in_w, out_w,
                                             xqb, xkb, xvb, wib, wob);

    qkv_gemm_kernel<<<768, 256, 0, stream>>>(xqb, xkb, xvb, wib, in_b, qo, ko, vto);

    attn_mfma_kernel<<<1024, 256, 0, stream>>>(qo, ko, vto, cw);

    out_gemm_kernel<<<256, 256, 0, stream>>>(cw, wob, out_b, (float*)d_out);
}